// Round 7
// baseline (317.092 us; speedup 1.0000x reference)
//
#include <hip/hip_runtime.h>
#include <cfloat>
#include <cmath>

#define NB 8
#define CC 128
#define HH 45
#define WW 60
#define HWP 2700      // H*W
#define KNN 16
#define H0 360
#define W0 480
#define NT 43         // ceil(2700/64) candidates per lane
#define MROWS 21600   // NB * HWP

typedef __bf16 bf16_8 __attribute__((ext_vector_type(8)));
typedef __bf16 bf16_4 __attribute__((ext_vector_type(4)));
typedef float  f32x4  __attribute__((ext_vector_type(4)));

// ---------------------------------------------------------------------------
// 1) Transpose (N,128,HW) -> (N,HW,128) channel-last
// ---------------------------------------------------------------------------
__global__ void transpose_cl(const float* __restrict__ in, float* __restrict__ out) {
    __shared__ float tile[32][33];
    int n = blockIdx.z;
    int c0 = blockIdx.y * 32;
    int p0 = blockIdx.x * 32;
    int tx = threadIdx.x & 31, ty = threadIdx.x >> 5;   // 32 x 8
    #pragma unroll
    for (int r = 0; r < 32; r += 8) {
        int c = c0 + ty + r, p = p0 + tx;
        tile[ty + r][tx] = (p < HWP) ? in[((size_t)n * CC + c) * HWP + p] : 0.f;
    }
    __syncthreads();
    #pragma unroll
    for (int r = 0; r < 32; r += 8) {
        int p = p0 + ty + r, c = c0 + tx;
        if (p < HWP) out[((size_t)n * HWP + p) * CC + c] = tile[tx][ty + r];
    }
}

// ---------------------------------------------------------------------------
// 2) Median pool 8x8: bitonic sort 64 lanes ascending, lane 31 = lower median
// ---------------------------------------------------------------------------
__global__ void median_pool(const float* __restrict__ xy, const float* __restrict__ orig,
                            float* __restrict__ proj) {
    int w = blockIdx.x * 4 + (threadIdx.x >> 6);
    int lane = threadIdx.x & 63;
    int n = w / (3 * HWP);
    int rem = w % (3 * HWP);
    int c = rem / HWP;
    int b = rem % HWP;
    const float* src = (c < 2) ? (xy + ((size_t)n * 2 + c) * H0 * W0)
                               : (orig + ((size_t)n * 4 + 3) * H0 * W0);
    int by = b / WW, bx = b % WW;
    int r = lane >> 3, col = lane & 7;
    float v = src[(by * 8 + r) * W0 + bx * 8 + col];
    #pragma unroll
    for (int k = 2; k <= 64; k <<= 1) {
        #pragma unroll
        for (int j2 = k >> 1; j2 >= 1; j2 >>= 1) {
            float p = __shfl_xor(v, j2, 64);
            bool dir = (lane & k) == 0;
            bool low = (lane & j2) == 0;
            v = (dir == low) ? fminf(v, p) : fmaxf(v, p);
        }
    }
    if (lane == 31) proj[(size_t)c * (NB * HWP) + (size_t)n * HWP + b] = v;
}

// ---------------------------------------------------------------------------
// 3) KNN — wave64/row, occupancy-tuned:
//    * pts stored float3 in LDS (sq recomputed inline, bit-identical expr)
//    * sd kept as packed u16 conservative upper bounds (2 per VGPR)
//    * filter vs inflated threshold (provable superset); survivors' exact
//      s/d recomputed from pts before the exact (d,idx) bitonic sort
//    * register-lean lex-rescan fallback (cnt outside [16,64]; never in practice)
// ---------------------------------------------------------------------------
__global__ void __launch_bounds__(512, 8) knn_kernel(const float* __restrict__ proj,
                                                     int* __restrict__ knn) {
#pragma clang fp contract(off)
    __shared__ float ptsf[HWP * 3];                // x,y,z interleaved
    __shared__ int sbufj[8][64];                   // survivor indices per wave
    int n = blockIdx.y;
    const float* px = proj + (size_t)n * HWP;
    const float* py = proj + (size_t)NB * HWP + (size_t)n * HWP;
    const float* pz = proj + (size_t)2 * NB * HWP + (size_t)n * HWP;
    for (int t = threadIdx.x; t < HWP; t += 512) {
        ptsf[t * 3 + 0] = px[t];
        ptsf[t * 3 + 1] = py[t];
        ptsf[t * 3 + 2] = pz[t];
    }
    __syncthreads();

    int wave = threadIdx.x >> 6;
    int lane = threadIdx.x & 63;
    int i = blockIdx.x * 8 + wave;                 // row (338*8 >= 2700)
    if (i >= HWP) return;                          // no syncs after this point
    float xi = ptsf[i * 3], yi = ptsf[i * 3 + 1], zi = ptsf[i * 3 + 2];
    float sqi = (xi * xi + yi * yi) + zi * zi;     // mirrors jnp.sum(proj*proj,-1)

    // ---- Pass A: squared distances; track lane-min; pack u16 upper bounds ----
    unsigned int sdp[22];
    float mn = FLT_MAX;
    #pragma unroll
    for (int t = 0; t < NT; ++t) {
        int j = lane + t * 64;
        unsigned int u = 0xFFFFu;
        if (j < HWP) {
            float xj = ptsf[j * 3], yj = ptsf[j * 3 + 1], zj = ptsf[j * 3 + 2];
            float sqj = (xj * xj + yj * yj) + zj * zj;
            float r = fmaf(zi, zj, fmaf(yi, yj, xi * xj));
            float s = (sqi + sqj) - 2.0f * r;
            mn = fminf(mn, s);
            float sc = fmaxf(s, 0.f);
            u = (__float_as_uint(sc) + 0xFFFFu) >> 16;   // >= sc, <= sc*(1+2^-7)
        }
        if (t & 1) sdp[t >> 1] |= (u << 16);
        else       sdp[t >> 1] = u;
    }

    // ---- Bitonic sort the 64 lane minima ascending; M_s = rank 15 ----
    float v = mn;
    #pragma unroll
    for (int k = 2; k <= 64; k <<= 1) {
        #pragma unroll
        for (int j2 = k >> 1; j2 >= 1; j2 >>= 1) {
            float p = __shfl_xor(v, j2, 64);
            bool dir = (lane & k) == 0;
            bool low = (lane & j2) == 0;
            v = (dir == low) ? fminf(v, p) : fmaxf(v, p);
        }
    }
    float M_s = __shfl(v, 15, 64);
    float M_test = (M_s > 0.f) ? (M_s * 1.0000005f + 1e-37f) : 0.0f;
    float M_t2 = M_test * 1.009f;                  // cover u16 round-up slack
    unsigned int M_bits = __float_as_uint(M_t2);

    // ---- Pass B: ballot-compact survivor indices into LDS ----
    int cnt = 0;
    #pragma unroll
    for (int t = 0; t < NT; ++t) {
        unsigned int u = (t & 1) ? (sdp[t >> 1] >> 16) : (sdp[t >> 1] & 0xFFFFu);
        bool pred = (u << 16) <= M_bits;           // float cmp via bits (both >= +0)
        unsigned long long b = __ballot(pred);
        if (b) {
            int off = cnt + (int)__popcll(b & ((1ull << lane) - 1ull));
            if (pred && off < 64) sbufj[wave][off] = lane + t * 64;
            cnt += (int)__popcll(b);
        }
    }

    int myj = 0;
    if (cnt >= KNN && cnt <= 64) {
        // ---- exact (d, idx) keys for survivors; 64-wide u64 bitonic sort ----
        unsigned long long key = ~0ull;
        if (lane < cnt) {
            int j = sbufj[wave][lane];
            float xj = ptsf[j * 3], yj = ptsf[j * 3 + 1], zj = ptsf[j * 3 + 2];
            float sqj = (xj * xj + yj * yj) + zj * zj;
            float r = fmaf(zi, zj, fmaf(yi, yj, xi * xj));
            float s = (sqi + sqj) - 2.0f * r;
            float d = sqrtf(fmaxf(s, 0.f));
            key = ((unsigned long long)__float_as_uint(d) << 32) | (unsigned int)j;
        }
        #pragma unroll
        for (int k = 2; k <= 64; k <<= 1) {
            #pragma unroll
            for (int j2 = k >> 1; j2 >= 1; j2 >>= 1) {
                unsigned long long p = __shfl_xor(key, j2, 64);
                bool dir = (lane & k) == 0;
                bool low = (lane & j2) == 0;
                bool keepmin = (dir == low);
                bool pless = p < key;
                key = (pless == keepmin) ? p : key;
            }
        }
        myj = (int)(unsigned int)(key & 0xffffffffull);
    } else {
        // ---- rare fallback: 16 rounds of lex-argmin rescan (low-register) ----
        float lastd = -FLT_MAX; int lastj = -1;
        #pragma unroll 1
        for (int r = 0; r < KNN; ++r) {
            float bd = FLT_MAX; int bj = 0x7fffffff;
            #pragma unroll 1
            for (int t = 0; t < NT; ++t) {
                int j = lane + t * 64;
                if (j < HWP) {
                    float xj = ptsf[j * 3], yj = ptsf[j * 3 + 1], zj = ptsf[j * 3 + 2];
                    float sqj = (xj * xj + yj * yj) + zj * zj;
                    float rr = fmaf(zi, zj, fmaf(yi, yj, xi * xj));
                    float s = (sqi + sqj) - 2.0f * rr;
                    float d = sqrtf(fmaxf(s, 0.f));
                    bool gt = (d > lastd) || (d == lastd && j > lastj);
                    bool lt = (d < bd) || (d == bd && j < bj);
                    if (gt && lt) { bd = d; bj = j; }
                }
            }
            float md = bd; int mj = bj;
            #pragma unroll
            for (int off = 32; off >= 1; off >>= 1) {
                float od = __shfl_xor(md, off, 64);
                int oj = __shfl_xor(mj, off, 64);
                if (od < md || (od == md && oj < mj)) { md = od; mj = oj; }
            }
            if (lane == r) myj = mj;
            lastd = md; lastj = mj;
        }
    }
    if (lane < KNN)
        knn[((size_t)n * HWP + i) * KNN + lane] = myj;
}

// ---------------------------------------------------------------------------
// 4) One prep kernel: split g0/g1/q weights into hi/lo MFMA fragments +
//    swizzle conv weights into B-fragment order.
// ---------------------------------------------------------------------------
template <int K>
__device__ __forceinline__ void wsplit_body(const float* __restrict__ Wt,
                                            __bf16* __restrict__ wh,
                                            __bf16* __restrict__ wl,
                                            int bx, int tid) {
    int t = bx * 256 + tid;
    int j = t & 7;
    int lane = (t >> 3) & 63;
    int nt = (t >> 9) & 7;
    int kc = t >> 12;
    int oc = nt * 16 + (lane & 15);
    int k = kc * 32 + (lane >> 4) * 8 + j;
    float v = Wt[(size_t)oc * K + k];
    __bf16 hi = (__bf16)v;
    wh[t] = hi;
    wl[t] = (__bf16)(v - (float)hi);
}

__global__ void prep_all(const float* __restrict__ g_w0, const float* __restrict__ g_w1,
                         const float* __restrict__ q_w, const float* __restrict__ conv_w,
                         __bf16* __restrict__ g0h, __bf16* __restrict__ g0l,
                         __bf16* __restrict__ g1h, __bf16* __restrict__ g1l,
                         __bf16* __restrict__ qh, __bf16* __restrict__ ql,
                         __bf16* __restrict__ w_frag) {
    int bx = blockIdx.x, tid = threadIdx.x;
    if (bx < 64)        wsplit_body<128>(g_w0, g0h, g0l, bx, tid);
    else if (bx < 128)  wsplit_body<128>(g_w1, g1h, g1l, bx - 64, tid);
    else if (bx < 256)  wsplit_body<256>(q_w, qh, ql, bx - 128, tid);
    else {
        int t = (bx - 256) * 256 + tid;              // 294,912
        int j = t & 7;
        int lane = (t >> 3) & 63;
        int ntile = (t >> 9) & 7;
        int icc = (t >> 12) & 7;
        int tap = t >> 15;
        int oc = ntile * 16 + (lane & 15);
        int ic = icc * 32 + (lane >> 4) * 8 + j;
        w_frag[t] = (__bf16)conv_w[((size_t)oc * 256 + ic) * 9 + tap];
    }
}

// ---------------------------------------------------------------------------
// 5) Shared GEMM layer: 32 px x 128 oc, A-operand = weights (M=oc), B =
//    activations from LDS fp32 [pix][132] split hi/lo in-register.
// ---------------------------------------------------------------------------
__device__ __forceinline__ void layer_32x128(
    const float* __restrict__ src,                 // LDS [32][132] fp32
    const __bf16* __restrict__ wh, const __bf16* __restrict__ wl,
    int wave, int lane, int kc_base, f32x4 acc[2][2]) {
    int quad = lane >> 4, lm = lane & 15;
    const bf16_8* wh8 = (const bf16_8*)wh;
    const bf16_8* wl8 = (const bf16_8*)wl;
    #pragma unroll
    for (int kc = 0; kc < 4; ++kc) {
        bf16_8 bh[2], bl[2];
        #pragma unroll
        for (int nt = 0; nt < 2; ++nt) {
            const float* p = &src[(nt * 16 + lm) * 132 + kc * 32 + quad * 8];
            float4 v0 = *(const float4*)p;
            float4 v1 = *(const float4*)(p + 4);
            float vs[8] = {v0.x, v0.y, v0.z, v0.w, v1.x, v1.y, v1.z, v1.w};
            #pragma unroll
            for (int e = 0; e < 8; ++e) {
                __bf16 hi = (__bf16)vs[e];
                bh[nt][e] = hi;
                bl[nt][e] = (__bf16)(vs[e] - (float)hi);
            }
        }
        bf16_8 ah[2], al[2];
        #pragma unroll
        for (int mt = 0; mt < 2; ++mt) {
            size_t idx = ((size_t)(kc_base + kc) * 8 + (wave * 2 + mt)) * 64 + lane;
            ah[mt] = wh8[idx];
            al[mt] = wl8[idx];
        }
        #pragma unroll
        for (int mt = 0; mt < 2; ++mt)
            #pragma unroll
            for (int nt = 0; nt < 2; ++nt) {
                acc[mt][nt] = __builtin_amdgcn_mfma_f32_16x16x32_bf16(ah[mt], bh[nt], acc[mt][nt], 0, 0, 0);
                acc[mt][nt] = __builtin_amdgcn_mfma_f32_16x16x32_bf16(ah[mt], bl[nt], acc[mt][nt], 0, 0, 0);
                acc[mt][nt] = __builtin_amdgcn_mfma_f32_16x16x32_bf16(al[mt], bh[nt], acc[mt][nt], 0, 0, 0);
            }
    }
}

// ---------------------------------------------------------------------------
// 5a) Fused g-MLP: tgb = prelu(g1(prelu(g0(A)))) as bf16, intermediate in LDS
// ---------------------------------------------------------------------------
__global__ void __launch_bounds__(256) fused_g(
    const float* __restrict__ Ain,
    const __bf16* __restrict__ w0h, const __bf16* __restrict__ w0l,
    const float* __restrict__ b0, const float* __restrict__ a0p,
    const __bf16* __restrict__ w1h, const __bf16* __restrict__ w1l,
    const float* __restrict__ b1, const float* __restrict__ a1p,
    __bf16* __restrict__ tgb) {
    __shared__ float albuf[32 * 132];
    __shared__ float inter[32 * 132];
    int r0 = blockIdx.x * 32;
    int tid = threadIdx.x;
    int wave = tid >> 6, lane = tid & 63;
    int quad = lane >> 4, lm = lane & 15;
    for (int t = tid; t < 1024; t += 256) {
        int row = t >> 5, c4 = (t & 31) * 4;
        *(float4*)&albuf[row * 132 + c4] = *(const float4*)&Ain[(size_t)(r0 + row) * 128 + c4];
    }
    __syncthreads();
    // layer 0
    {
        f32x4 acc[2][2] = {};
        layer_32x128(albuf, w0h, w0l, wave, lane, 0, acc);
        float alpha = a0p[0];
        #pragma unroll
        for (int mt = 0; mt < 2; ++mt) {
            int oc0 = wave * 32 + mt * 16 + quad * 4;
            float4 bb = *(const float4*)&b0[oc0];
            float bv[4] = {bb.x, bb.y, bb.z, bb.w};
            #pragma unroll
            for (int nt = 0; nt < 2; ++nt) {
                float4 o;
                float* op = (float*)&o;
                #pragma unroll
                for (int reg = 0; reg < 4; ++reg) {
                    float vv = acc[mt][nt][reg] + bv[reg];
                    op[reg] = (vv >= 0.f) ? vv : alpha * vv;
                }
                *(float4*)&inter[(nt * 16 + lm) * 132 + oc0] = o;
            }
        }
    }
    __syncthreads();
    // layer 1
    {
        f32x4 acc[2][2] = {};
        layer_32x128(inter, w1h, w1l, wave, lane, 0, acc);
        float alpha = a1p[0];
        #pragma unroll
        for (int mt = 0; mt < 2; ++mt) {
            int oc0 = wave * 32 + mt * 16 + quad * 4;
            float4 bb = *(const float4*)&b1[oc0];
            float bv[4] = {bb.x, bb.y, bb.z, bb.w};
            #pragma unroll
            for (int nt = 0; nt < 2; ++nt) {
                bf16_4 o;
                #pragma unroll
                for (int reg = 0; reg < 4; ++reg) {
                    float vv = acc[mt][nt][reg] + bv[reg];
                    vv = (vv >= 0.f) ? vv : alpha * vv;
                    o[reg] = (__bf16)vv;
                }
                *(bf16_4*)&tgb[(size_t)(r0 + nt * 16 + lm) * 128 + oc0] = o;
            }
        }
    }
}

// ---------------------------------------------------------------------------
// 5b) Fused gather-mean + q-GEMM: h_out = prelu([A | mean16(tgb)] @ q^T + b)
// ---------------------------------------------------------------------------
__global__ void __launch_bounds__(256) fused_q(
    const float* __restrict__ Ain, const __bf16* __restrict__ tgb,
    const int* __restrict__ knn_idx,
    const __bf16* __restrict__ qh, const __bf16* __restrict__ ql,
    const float* __restrict__ qb, const float* __restrict__ qap,
    float* __restrict__ hout) {
    __shared__ float hlds[32 * 132];
    __shared__ float mlds[32 * 132];
    int r0 = blockIdx.x * 32;
    int tid = threadIdx.x;
    int wave = tid >> 6, lane = tid & 63;
    int quad = lane >> 4, lm = lane & 15;
    for (int t = tid; t < 1024; t += 256) {
        int row = t >> 5, c4 = (t & 31) * 4;
        *(float4*)&hlds[row * 132 + c4] = *(const float4*)&Ain[(size_t)(r0 + row) * 128 + c4];
    }
    {   // gather + mean: thread handles (pix, oct0) and (pix, oct0+1)
        int pix = tid >> 3;
        int oct0 = (tid & 7) * 2;
        int grow = r0 + pix;
        int nimg = grow / HWP;
        const int* kn = knn_idx + (size_t)grow * KNN;
        const __bf16* tbase = tgb + ((size_t)nimg * HWP) * 128;
        float a0[8] = {}, a1[8] = {};
        #pragma unroll
        for (int k = 0; k < KNN; ++k) {
            int j = kn[k];
            const __bf16* srcp = tbase + (size_t)j * 128 + oct0 * 8;
            bf16_8 v0 = *(const bf16_8*)srcp;
            bf16_8 v1 = *(const bf16_8*)(srcp + 8);
            #pragma unroll
            for (int e = 0; e < 8; ++e) { a0[e] += (float)v0[e]; a1[e] += (float)v1[e]; }
        }
        const float s = 1.f / 16.f;
        float* dst = &mlds[pix * 132 + oct0 * 8];
        float4 o0 = {a0[0] * s, a0[1] * s, a0[2] * s, a0[3] * s};
        float4 o1 = {a0[4] * s, a0[5] * s, a0[6] * s, a0[7] * s};
        float4 o2 = {a1[0] * s, a1[1] * s, a1[2] * s, a1[3] * s};
        float4 o3 = {a1[4] * s, a1[5] * s, a1[6] * s, a1[7] * s};
        *(float4*)(dst) = o0; *(float4*)(dst + 4) = o1;
        *(float4*)(dst + 8) = o2; *(float4*)(dst + 12) = o3;
    }
    __syncthreads();
    f32x4 acc[2][2] = {};
    layer_32x128(hlds, qh, ql, wave, lane, 0, acc);   // k 0..127 (h part)
    layer_32x128(mlds, qh, ql, wave, lane, 4, acc);   // k 128..255 (m part)
    float alpha = qap[0];
    #pragma unroll
    for (int mt = 0; mt < 2; ++mt) {
        int oc0 = wave * 32 + mt * 16 + quad * 4;
        float4 bb = *(const float4*)&qb[oc0];
        float bv[4] = {bb.x, bb.y, bb.z, bb.w};
        #pragma unroll
        for (int nt = 0; nt < 2; ++nt) {
            float4 o;
            float* op = (float*)&o;
            #pragma unroll
            for (int reg = 0; reg < 4; ++reg) {
                float vv = acc[mt][nt][reg] + bv[reg];
                op[reg] = (vv >= 0.f) ? vv : alpha * vv;
            }
            *(float4*)&hout[(size_t)(r0 + nt * 16 + lm) * 128 + oc0] = o;
        }
    }
}

// ---------------------------------------------------------------------------
// 6a) Pack concat(cnn_cl, h) -> zero-padded channel-last bf16 (N,47,68,256)
// ---------------------------------------------------------------------------
__global__ void pack_input(const float* __restrict__ cnn_cl, const float* __restrict__ h,
                           __bf16* __restrict__ pad_in) {
    int t = blockIdx.x * 256 + threadIdx.x;      // 818,176 threads, 8 ch each
    int cg = t & 31;
    int s = t >> 5;
    int q = s % 68; s /= 68;
    int p = s % 47;
    int n = s / 47;
    int y = p - 1, x = q - 1;
    bf16_8 v = {};
    if (y >= 0 && y < HH && x >= 0 && x < WW) {
        int c0 = cg * 8;
        const float* src = (c0 < 128)
            ? (cnn_cl + (((size_t)n * HWP + y * WW + x) * 128 + c0))
            : (h      + (((size_t)n * HWP + y * WW + x) * 128 + (c0 - 128)));
        float4 l0 = *(const float4*)&src[0];
        float4 l1 = *(const float4*)&src[4];
        v[0] = (__bf16)l0.x; v[1] = (__bf16)l0.y; v[2] = (__bf16)l0.z; v[3] = (__bf16)l0.w;
        v[4] = (__bf16)l1.x; v[5] = (__bf16)l1.y; v[6] = (__bf16)l1.z; v[7] = (__bf16)l1.w;
    }
    ((bf16_8*)pad_in)[t] = v;
}

// ---------------------------------------------------------------------------
// 6b) Conv 3x3 MFMA, oc-split for occupancy: grid (y, oc-half, n), 720 blocks.
//     Wave: wm = M-half (32 px), wq = 32-oc group within the 64-oc half.
// ---------------------------------------------------------------------------
__global__ void __launch_bounds__(256) conv_mfma(
    const __bf16* __restrict__ pad_in,   // (N,47,68,256)
    const __bf16* __restrict__ w_frag,   // fragment-ordered weights
    const float* __restrict__ bias,
    float* __restrict__ out) {           // (N,128,45,60)
    __shared__ __bf16 alds[3 * 66 * 32];         // [dy][px 0..65][ic 0..31]
    int y = blockIdx.x;
    int oh = blockIdx.y;
    int n = blockIdx.z;
    int tid = threadIdx.x;
    int wave = tid >> 6, lane = tid & 63;
    int wm = wave & 1, wq = wave >> 1;
    int quad = lane >> 4, lm = lane & 15;

    f32x4 acc[2][2] = {};
    const bf16_8* wf = (const bf16_8*)w_frag;

    for (int icc = 0; icc < 8; ++icc) {
        __syncthreads();
        for (int t = tid; t < 792; t += 256) {   // 3*66*4 x 16B
            int cq = t & 3;
            int xp = (t >> 2) % 66;
            int dy = (t >> 2) / 66;
            size_t src = (((size_t)n * 47 + (y + dy)) * 68 + xp) * 256 + icc * 32 + cq * 8;
            *(bf16_8*)&alds[(dy * 66 + xp) * 32 + cq * 8] = *(const bf16_8*)&pad_in[src];
        }
        __syncthreads();
        #pragma unroll
        for (int tap = 0; tap < 9; ++tap) {
            int ky = tap / 3, kx = tap % 3;
            bf16_8 b[2], a[2];
            #pragma unroll
            for (int nt = 0; nt < 2; ++nt)
                b[nt] = wf[(((tap * 8 + icc) * 8) + (oh * 4 + wq * 2 + nt)) * 64 + lane];
            #pragma unroll
            for (int mt = 0; mt < 2; ++mt)
                a[mt] = *(const bf16_8*)&alds[(ky * 66 + (wm * 32 + mt * 16 + lm + kx)) * 32 + quad * 8];
            #pragma unroll
            for (int mt = 0; mt < 2; ++mt)
                #pragma unroll
                for (int nt = 0; nt < 2; ++nt)
                    acc[mt][nt] = __builtin_amdgcn_mfma_f32_16x16x32_bf16(
                        a[mt], b[nt], acc[mt][nt], 0, 0, 0);
        }
    }
    #pragma unroll
    for (int mt = 0; mt < 2; ++mt) {
        int x0 = wm * 32 + mt * 16 + quad * 4;
        if (x0 >= WW) continue;
        #pragma unroll
        for (int nt = 0; nt < 2; ++nt) {
            int oc = (oh * 4 + wq * 2 + nt) * 16 + lm;
            float bb = bias[oc];
            f32x4 v = acc[mt][nt];
            v[0] += bb; v[1] += bb; v[2] += bb; v[3] += bb;
            *(f32x4*)&out[(((size_t)n * 128 + oc) * HH + y) * WW + x0] = v;
        }
    }
}

// ---------------------------------------------------------------------------
extern "C" void kernel_launch(void* const* d_in, const int* in_sizes, int n_in,
                              void* d_out, int out_size, void* d_ws, size_t ws_size,
                              hipStream_t stream) {
    const float* cnn    = (const float*)d_in[0];
    const float* orig   = (const float*)d_in[1];
    const float* xy     = (const float*)d_in[2];
    const float* g_w0   = (const float*)d_in[3];
    const float* g_b0   = (const float*)d_in[4];
    const float* g_a0   = (const float*)d_in[5];
    const float* g_w1   = (const float*)d_in[6];
    const float* g_b1   = (const float*)d_in[7];
    const float* g_a1   = (const float*)d_in[8];
    const float* q_w    = (const float*)d_in[9];
    const float* q_b    = (const float*)d_in[10];
    const float* q_a    = (const float*)d_in[11];
    const float* conv_w = (const float*)d_in[12];
    const float* conv_b = (const float*)d_in[13];
    float* out = (float*)d_out;

    float* ws = (float*)d_ws;
    const size_t S = (size_t)MROWS * CC;        // 2,764,800
    float*  cnn_cl = ws;                        // [0, S)
    float*  h      = ws + S;                    // [S, 2S)
    float*  base   = ws + 2 * S;
    __bf16* tgb    = (__bf16*)base;             // MROWS*128 bf16 = 1,382,400 fl
    float*  proj   = base + 1382400;            // 64,800 fl
    int*    knn_i  = (int*)(base + 1382400 + 64800);          // 345,600 slots
    __bf16* wfb    = (__bf16*)(base + 1382400 + 64800 + 345600);
    __bf16* g0h = wfb;            __bf16* g0l = wfb + 16384;
    __bf16* g1h = wfb + 32768;    __bf16* g1l = wfb + 49152;
    __bf16* qh  = wfb + 65536;    __bf16* ql  = wfb + 98304;  // 131,072 bf16
    __bf16* w_frag = wfb + 131072;                            // 294,912 bf16
    __bf16* pad_in = w_frag + 294912;                         // 6,545,408 bf16

    transpose_cl<<<dim3(85, 4, NB), 256, 0, stream>>>(cnn, cnn_cl);
    median_pool<<<16200, 256, 0, stream>>>(xy, orig, proj);
    knn_kernel<<<dim3(338, NB), 512, 0, stream>>>(proj, knn_i);
    prep_all<<<1408, 256, 0, stream>>>(g_w0, g_w1, q_w, conv_w,
                                       g0h, g0l, g1h, g1l, qh, ql, w_frag);

    // GNN iteration 1 (h = cnn_cl)
    fused_g<<<675, 256, 0, stream>>>(cnn_cl, g0h, g0l, g_b0, g_a0,
                                     g1h, g1l, g_b1, g_a1, tgb);
    fused_q<<<675, 256, 0, stream>>>(cnn_cl, tgb, knn_i, qh, ql, q_b, q_a, h);

    // GNN iteration 2
    fused_g<<<675, 256, 0, stream>>>(h, g0h, g0l, g_b0, g_a0,
                                     g1h, g1l, g_b1, g_a1, tgb);
    fused_q<<<675, 256, 0, stream>>>(h, tgb, knn_i, qh, ql, q_b, q_a, h);

    // Conv epilogue
    pack_input<<<3196, 256, 0, stream>>>(cnn_cl, h, pad_in);
    conv_mfma<<<dim3(HH, 2, NB), 256, 0, stream>>>(pad_in, w_frag, conv_b, out);
}

// Round 8
// 270.319 us; speedup vs baseline: 1.1730x; 1.1730x over previous
//
#include <hip/hip_runtime.h>
#include <cfloat>
#include <cmath>

#define NB 8
#define CC 128
#define HH 45
#define WW 60
#define HWP 2700      // H*W
#define KNN 16
#define H0 360
#define W0 480
#define NT 43         // ceil(2700/64) candidates per lane
#define MROWS 21600   // NB * HWP

typedef __bf16 bf16_8 __attribute__((ext_vector_type(8)));
typedef __bf16 bf16_4 __attribute__((ext_vector_type(4)));
typedef float  f32x4  __attribute__((ext_vector_type(4)));

// ---------------------------------------------------------------------------
// 1) Transpose (N,128,HW) -> (N,HW,128) channel-last
// ---------------------------------------------------------------------------
__global__ void transpose_cl(const float* __restrict__ in, float* __restrict__ out) {
    __shared__ float tile[32][33];
    int n = blockIdx.z;
    int c0 = blockIdx.y * 32;
    int p0 = blockIdx.x * 32;
    int tx = threadIdx.x & 31, ty = threadIdx.x >> 5;   // 32 x 8
    #pragma unroll
    for (int r = 0; r < 32; r += 8) {
        int c = c0 + ty + r, p = p0 + tx;
        tile[ty + r][tx] = (p < HWP) ? in[((size_t)n * CC + c) * HWP + p] : 0.f;
    }
    __syncthreads();
    #pragma unroll
    for (int r = 0; r < 32; r += 8) {
        int p = p0 + ty + r, c = c0 + tx;
        if (p < HWP) out[((size_t)n * HWP + p) * CC + c] = tile[tx][ty + r];
    }
}

// ---------------------------------------------------------------------------
// 2) Median pool 8x8: bitonic sort 64 lanes ascending, lane 31 = lower median
// ---------------------------------------------------------------------------
__global__ void median_pool(const float* __restrict__ xy, const float* __restrict__ orig,
                            float* __restrict__ proj) {
    int w = blockIdx.x * 4 + (threadIdx.x >> 6);
    int lane = threadIdx.x & 63;
    int n = w / (3 * HWP);
    int rem = w % (3 * HWP);
    int c = rem / HWP;
    int b = rem % HWP;
    const float* src = (c < 2) ? (xy + ((size_t)n * 2 + c) * H0 * W0)
                               : (orig + ((size_t)n * 4 + 3) * H0 * W0);
    int by = b / WW, bx = b % WW;
    int r = lane >> 3, col = lane & 7;
    float v = src[(by * 8 + r) * W0 + bx * 8 + col];
    #pragma unroll
    for (int k = 2; k <= 64; k <<= 1) {
        #pragma unroll
        for (int j2 = k >> 1; j2 >= 1; j2 >>= 1) {
            float p = __shfl_xor(v, j2, 64);
            bool dir = (lane & k) == 0;
            bool low = (lane & j2) == 0;
            v = (dir == low) ? fminf(v, p) : fmaxf(v, p);
        }
    }
    if (lane == 31) proj[(size_t)c * (NB * HWP) + (size_t)n * HWP + b] = v;
}

// ---------------------------------------------------------------------------
// 3) KNN — wave64/row. float4 pts in LDS (one ds_read_b128/candidate),
//    packed-u16 conservative bounds (2/VGPR), survivor exact recompute +
//    64-wide u64 bitonic sort. launch_bounds(512,6): VGPR cap 85 — fits
//    without spills (round-7's (512,8) forced 330 MB of scratch traffic).
// ---------------------------------------------------------------------------
__global__ void __launch_bounds__(512, 6) knn_kernel(const float* __restrict__ proj,
                                                     int* __restrict__ knn) {
#pragma clang fp contract(off)
    __shared__ float4 pts[HWP];                    // (x, y, z, sq) per candidate
    __shared__ int sbufj[8][64];                   // survivor indices per wave
    int n = blockIdx.y;
    const float* px = proj + (size_t)n * HWP;
    const float* py = proj + (size_t)NB * HWP + (size_t)n * HWP;
    const float* pz = proj + (size_t)2 * NB * HWP + (size_t)n * HWP;
    for (int t = threadIdx.x; t < HWP; t += 512) {
        float x = px[t], y = py[t], z = pz[t];
        float4 p;
        p.x = x; p.y = y; p.z = z;
        p.w = (x * x + y * y) + z * z;             // mirrors jnp.sum(proj*proj,-1)
        pts[t] = p;
    }
    __syncthreads();

    int wave = threadIdx.x >> 6;
    int lane = threadIdx.x & 63;
    int i = blockIdx.x * 8 + wave;                 // row (338*8 >= 2700)
    if (i >= HWP) return;                          // no syncs after this point
    float4 pi = pts[i];
    float xi = pi.x, yi = pi.y, zi = pi.z, sqi = pi.w;

    // ---- Pass A: squared distances; lane min; packed u16 upper bounds ----
    unsigned int sdp[22];
    float mn = FLT_MAX;
    #pragma unroll
    for (int t = 0; t < NT; ++t) {
        int j = lane + t * 64;
        unsigned int u = 0xFFFFu;
        if (j < HWP) {
            float4 pj = pts[j];
            float r = fmaf(zi, pj.z, fmaf(yi, pj.y, xi * pj.x));
            float s = (sqi + pj.w) - 2.0f * r;
            mn = fminf(mn, s);
            float sc = fmaxf(s, 0.f);
            u = (__float_as_uint(sc) + 0xFFFFu) >> 16;   // >= sc, <= sc*(1+2^-7)
        }
        if (t & 1) sdp[t >> 1] |= (u << 16);
        else       sdp[t >> 1] = u;
    }

    // ---- Bitonic sort the 64 lane minima ascending; M_s = rank 15 ----
    float v = mn;
    #pragma unroll
    for (int k = 2; k <= 64; k <<= 1) {
        #pragma unroll
        for (int j2 = k >> 1; j2 >= 1; j2 >>= 1) {
            float p = __shfl_xor(v, j2, 64);
            bool dir = (lane & k) == 0;
            bool low = (lane & j2) == 0;
            v = (dir == low) ? fminf(v, p) : fmaxf(v, p);
        }
    }
    float M_s = __shfl(v, 15, 64);
    float M_test = (M_s > 0.f) ? (M_s * 1.0000005f + 1e-37f) : 0.0f;
    float M_t2 = M_test * 1.009f;                  // cover u16 round-up slack
    unsigned int M_bits = __float_as_uint(M_t2);

    // ---- Pass B: ballot-compact survivor indices into LDS ----
    int cnt = 0;
    #pragma unroll
    for (int t = 0; t < NT; ++t) {
        unsigned int u = (t & 1) ? (sdp[t >> 1] >> 16) : (sdp[t >> 1] & 0xFFFFu);
        bool pred = (u << 16) <= M_bits;           // float cmp via bits (both >= +0)
        unsigned long long b = __ballot(pred);
        if (b) {
            int off = cnt + (int)__popcll(b & ((1ull << lane) - 1ull));
            if (pred && off < 64) sbufj[wave][off] = lane + t * 64;
            cnt += (int)__popcll(b);
        }
    }

    int myj = 0;
    if (cnt >= KNN && cnt <= 64) {
        // ---- exact (d, idx) keys for survivors; 64-wide u64 bitonic sort ----
        unsigned long long key = ~0ull;
        if (lane < cnt) {
            int j = sbufj[wave][lane];
            float4 pj = pts[j];
            float r = fmaf(zi, pj.z, fmaf(yi, pj.y, xi * pj.x));
            float s = (sqi + pj.w) - 2.0f * r;
            float d = sqrtf(fmaxf(s, 0.f));
            key = ((unsigned long long)__float_as_uint(d) << 32) | (unsigned int)j;
        }
        #pragma unroll
        for (int k = 2; k <= 64; k <<= 1) {
            #pragma unroll
            for (int j2 = k >> 1; j2 >= 1; j2 >>= 1) {
                unsigned long long p = __shfl_xor(key, j2, 64);
                bool dir = (lane & k) == 0;
                bool low = (lane & j2) == 0;
                bool keepmin = (dir == low);
                bool pless = p < key;
                key = (pless == keepmin) ? p : key;
            }
        }
        myj = (int)(unsigned int)(key & 0xffffffffull);
    } else {
        // ---- rare fallback: 16 rounds of lex-argmin rescan (low-register) ----
        float lastd = -FLT_MAX; int lastj = -1;
        #pragma unroll 1
        for (int r = 0; r < KNN; ++r) {
            float bd = FLT_MAX; int bj = 0x7fffffff;
            #pragma unroll 1
            for (int t = 0; t < NT; ++t) {
                int j = lane + t * 64;
                if (j < HWP) {
                    float4 pj = pts[j];
                    float rr = fmaf(zi, pj.z, fmaf(yi, pj.y, xi * pj.x));
                    float s = (sqi + pj.w) - 2.0f * rr;
                    float d = sqrtf(fmaxf(s, 0.f));
                    bool gt = (d > lastd) || (d == lastd && j > lastj);
                    bool lt = (d < bd) || (d == bd && j < bj);
                    if (gt && lt) { bd = d; bj = j; }
                }
            }
            float md = bd; int mj = bj;
            #pragma unroll
            for (int off = 32; off >= 1; off >>= 1) {
                float od = __shfl_xor(md, off, 64);
                int oj = __shfl_xor(mj, off, 64);
                if (od < md || (od == md && oj < mj)) { md = od; mj = oj; }
            }
            if (lane == r) myj = mj;
            lastd = md; lastj = mj;
        }
    }
    if (lane < KNN)
        knn[((size_t)n * HWP + i) * KNN + lane] = myj;
}

// ---------------------------------------------------------------------------
// 4) One prep kernel: split g0/g1/q weights into hi/lo MFMA fragments +
//    swizzle conv weights into B-fragment order.
// ---------------------------------------------------------------------------
template <int K>
__device__ __forceinline__ void wsplit_body(const float* __restrict__ Wt,
                                            __bf16* __restrict__ wh,
                                            __bf16* __restrict__ wl,
                                            int bx, int tid) {
    int t = bx * 256 + tid;
    int j = t & 7;
    int lane = (t >> 3) & 63;
    int nt = (t >> 9) & 7;
    int kc = t >> 12;
    int oc = nt * 16 + (lane & 15);
    int k = kc * 32 + (lane >> 4) * 8 + j;
    float v = Wt[(size_t)oc * K + k];
    __bf16 hi = (__bf16)v;
    wh[t] = hi;
    wl[t] = (__bf16)(v - (float)hi);
}

__global__ void prep_all(const float* __restrict__ g_w0, const float* __restrict__ g_w1,
                         const float* __restrict__ q_w, const float* __restrict__ conv_w,
                         __bf16* __restrict__ g0h, __bf16* __restrict__ g0l,
                         __bf16* __restrict__ g1h, __bf16* __restrict__ g1l,
                         __bf16* __restrict__ qh, __bf16* __restrict__ ql,
                         __bf16* __restrict__ w_frag) {
    int bx = blockIdx.x, tid = threadIdx.x;
    if (bx < 64)        wsplit_body<128>(g_w0, g0h, g0l, bx, tid);
    else if (bx < 128)  wsplit_body<128>(g_w1, g1h, g1l, bx - 64, tid);
    else if (bx < 256)  wsplit_body<256>(q_w, qh, ql, bx - 128, tid);
    else {
        int t = (bx - 256) * 256 + tid;              // 294,912
        int j = t & 7;
        int lane = (t >> 3) & 63;
        int ntile = (t >> 9) & 7;
        int icc = (t >> 12) & 7;
        int tap = t >> 15;
        int oc = ntile * 16 + (lane & 15);
        int ic = icc * 32 + (lane >> 4) * 8 + j;
        w_frag[t] = (__bf16)conv_w[((size_t)oc * 256 + ic) * 9 + tap];
    }
}

// ---------------------------------------------------------------------------
// 5) Shared GEMM layer: 32 px x 128 oc, A-operand = weights (M=oc), B =
//    activations from LDS fp32 [pix][132] split hi/lo in-register.
// ---------------------------------------------------------------------------
__device__ __forceinline__ void layer_32x128(
    const float* __restrict__ src,                 // LDS [32][132] fp32
    const __bf16* __restrict__ wh, const __bf16* __restrict__ wl,
    int wave, int lane, int kc_base, f32x4 acc[2][2]) {
    int quad = lane >> 4, lm = lane & 15;
    const bf16_8* wh8 = (const bf16_8*)wh;
    const bf16_8* wl8 = (const bf16_8*)wl;
    #pragma unroll
    for (int kc = 0; kc < 4; ++kc) {
        bf16_8 bh[2], bl[2];
        #pragma unroll
        for (int nt = 0; nt < 2; ++nt) {
            const float* p = &src[(nt * 16 + lm) * 132 + kc * 32 + quad * 8];
            float4 v0 = *(const float4*)p;
            float4 v1 = *(const float4*)(p + 4);
            float vs[8] = {v0.x, v0.y, v0.z, v0.w, v1.x, v1.y, v1.z, v1.w};
            #pragma unroll
            for (int e = 0; e < 8; ++e) {
                __bf16 hi = (__bf16)vs[e];
                bh[nt][e] = hi;
                bl[nt][e] = (__bf16)(vs[e] - (float)hi);
            }
        }
        bf16_8 ah[2], al[2];
        #pragma unroll
        for (int mt = 0; mt < 2; ++mt) {
            size_t idx = ((size_t)(kc_base + kc) * 8 + (wave * 2 + mt)) * 64 + lane;
            ah[mt] = wh8[idx];
            al[mt] = wl8[idx];
        }
        #pragma unroll
        for (int mt = 0; mt < 2; ++mt)
            #pragma unroll
            for (int nt = 0; nt < 2; ++nt) {
                acc[mt][nt] = __builtin_amdgcn_mfma_f32_16x16x32_bf16(ah[mt], bh[nt], acc[mt][nt], 0, 0, 0);
                acc[mt][nt] = __builtin_amdgcn_mfma_f32_16x16x32_bf16(ah[mt], bl[nt], acc[mt][nt], 0, 0, 0);
                acc[mt][nt] = __builtin_amdgcn_mfma_f32_16x16x32_bf16(al[mt], bh[nt], acc[mt][nt], 0, 0, 0);
            }
    }
}

// ---------------------------------------------------------------------------
// 5a) Fused g-MLP: tgb = prelu(g1(prelu(g0(A)))) as bf16, intermediate in LDS
// ---------------------------------------------------------------------------
__global__ void __launch_bounds__(256) fused_g(
    const float* __restrict__ Ain,
    const __bf16* __restrict__ w0h, const __bf16* __restrict__ w0l,
    const float* __restrict__ b0, const float* __restrict__ a0p,
    const __bf16* __restrict__ w1h, const __bf16* __restrict__ w1l,
    const float* __restrict__ b1, const float* __restrict__ a1p,
    __bf16* __restrict__ tgb) {
    __shared__ float albuf[32 * 132];
    __shared__ float inter[32 * 132];
    int r0 = blockIdx.x * 32;
    int tid = threadIdx.x;
    int wave = tid >> 6, lane = tid & 63;
    int quad = lane >> 4, lm = lane & 15;
    for (int t = tid; t < 1024; t += 256) {
        int row = t >> 5, c4 = (t & 31) * 4;
        *(float4*)&albuf[row * 132 + c4] = *(const float4*)&Ain[(size_t)(r0 + row) * 128 + c4];
    }
    __syncthreads();
    // layer 0
    {
        f32x4 acc[2][2] = {};
        layer_32x128(albuf, w0h, w0l, wave, lane, 0, acc);
        float alpha = a0p[0];
        #pragma unroll
        for (int mt = 0; mt < 2; ++mt) {
            int oc0 = wave * 32 + mt * 16 + quad * 4;
            float4 bb = *(const float4*)&b0[oc0];
            float bv[4] = {bb.x, bb.y, bb.z, bb.w};
            #pragma unroll
            for (int nt = 0; nt < 2; ++nt) {
                float4 o;
                float* op = (float*)&o;
                #pragma unroll
                for (int reg = 0; reg < 4; ++reg) {
                    float vv = acc[mt][nt][reg] + bv[reg];
                    op[reg] = (vv >= 0.f) ? vv : alpha * vv;
                }
                *(float4*)&inter[(nt * 16 + lm) * 132 + oc0] = o;
            }
        }
    }
    __syncthreads();
    // layer 1
    {
        f32x4 acc[2][2] = {};
        layer_32x128(inter, w1h, w1l, wave, lane, 0, acc);
        float alpha = a1p[0];
        #pragma unroll
        for (int mt = 0; mt < 2; ++mt) {
            int oc0 = wave * 32 + mt * 16 + quad * 4;
            float4 bb = *(const float4*)&b1[oc0];
            float bv[4] = {bb.x, bb.y, bb.z, bb.w};
            #pragma unroll
            for (int nt = 0; nt < 2; ++nt) {
                bf16_4 o;
                #pragma unroll
                for (int reg = 0; reg < 4; ++reg) {
                    float vv = acc[mt][nt][reg] + bv[reg];
                    vv = (vv >= 0.f) ? vv : alpha * vv;
                    o[reg] = (__bf16)vv;
                }
                *(bf16_4*)&tgb[(size_t)(r0 + nt * 16 + lm) * 128 + oc0] = o;
            }
        }
    }
}

// ---------------------------------------------------------------------------
// 5b) Fused gather-mean + q-GEMM: h_out = prelu([A | mean16(tgb)] @ q^T + b)
// ---------------------------------------------------------------------------
__global__ void __launch_bounds__(256) fused_q(
    const float* __restrict__ Ain, const __bf16* __restrict__ tgb,
    const int* __restrict__ knn_idx,
    const __bf16* __restrict__ qh, const __bf16* __restrict__ ql,
    const float* __restrict__ qb, const float* __restrict__ qap,
    float* __restrict__ hout) {
    __shared__ float hlds[32 * 132];
    __shared__ float mlds[32 * 132];
    int r0 = blockIdx.x * 32;
    int tid = threadIdx.x;
    int wave = tid >> 6, lane = tid & 63;
    int quad = lane >> 4, lm = lane & 15;
    for (int t = tid; t < 1024; t += 256) {
        int row = t >> 5, c4 = (t & 31) * 4;
        *(float4*)&hlds[row * 132 + c4] = *(const float4*)&Ain[(size_t)(r0 + row) * 128 + c4];
    }
    {   // gather + mean: thread handles (pix, oct0) and (pix, oct0+1)
        int pix = tid >> 3;
        int oct0 = (tid & 7) * 2;
        int grow = r0 + pix;
        int nimg = grow / HWP;
        const int* kn = knn_idx + (size_t)grow * KNN;
        const __bf16* tbase = tgb + ((size_t)nimg * HWP) * 128;
        float a0[8] = {}, a1[8] = {};
        #pragma unroll
        for (int k = 0; k < KNN; ++k) {
            int j = kn[k];
            const __bf16* srcp = tbase + (size_t)j * 128 + oct0 * 8;
            bf16_8 v0 = *(const bf16_8*)srcp;
            bf16_8 v1 = *(const bf16_8*)(srcp + 8);
            #pragma unroll
            for (int e = 0; e < 8; ++e) { a0[e] += (float)v0[e]; a1[e] += (float)v1[e]; }
        }
        const float s = 1.f / 16.f;
        float* dst = &mlds[pix * 132 + oct0 * 8];
        float4 o0 = {a0[0] * s, a0[1] * s, a0[2] * s, a0[3] * s};
        float4 o1 = {a0[4] * s, a0[5] * s, a0[6] * s, a0[7] * s};
        float4 o2 = {a1[0] * s, a1[1] * s, a1[2] * s, a1[3] * s};
        float4 o3 = {a1[4] * s, a1[5] * s, a1[6] * s, a1[7] * s};
        *(float4*)(dst) = o0; *(float4*)(dst + 4) = o1;
        *(float4*)(dst + 8) = o2; *(float4*)(dst + 12) = o3;
    }
    __syncthreads();
    f32x4 acc[2][2] = {};
    layer_32x128(hlds, qh, ql, wave, lane, 0, acc);   // k 0..127 (h part)
    layer_32x128(mlds, qh, ql, wave, lane, 4, acc);   // k 128..255 (m part)
    float alpha = qap[0];
    #pragma unroll
    for (int mt = 0; mt < 2; ++mt) {
        int oc0 = wave * 32 + mt * 16 + quad * 4;
        float4 bb = *(const float4*)&qb[oc0];
        float bv[4] = {bb.x, bb.y, bb.z, bb.w};
        #pragma unroll
        for (int nt = 0; nt < 2; ++nt) {
            float4 o;
            float* op = (float*)&o;
            #pragma unroll
            for (int reg = 0; reg < 4; ++reg) {
                float vv = acc[mt][nt][reg] + bv[reg];
                op[reg] = (vv >= 0.f) ? vv : alpha * vv;
            }
            *(float4*)&hout[(size_t)(r0 + nt * 16 + lm) * 128 + oc0] = o;
        }
    }
}

// ---------------------------------------------------------------------------
// 6a) Pack concat(cnn_cl, h) -> zero-padded channel-last bf16 (N,47,68,256)
// ---------------------------------------------------------------------------
__global__ void pack_input(const float* __restrict__ cnn_cl, const float* __restrict__ h,
                           __bf16* __restrict__ pad_in) {
    int t = blockIdx.x * 256 + threadIdx.x;      // 818,176 threads, 8 ch each
    int cg = t & 31;
    int s = t >> 5;
    int q = s % 68; s /= 68;
    int p = s % 47;
    int n = s / 47;
    int y = p - 1, x = q - 1;
    bf16_8 v = {};
    if (y >= 0 && y < HH && x >= 0 && x < WW) {
        int c0 = cg * 8;
        const float* src = (c0 < 128)
            ? (cnn_cl + (((size_t)n * HWP + y * WW + x) * 128 + c0))
            : (h      + (((size_t)n * HWP + y * WW + x) * 128 + (c0 - 128)));
        float4 l0 = *(const float4*)&src[0];
        float4 l1 = *(const float4*)&src[4];
        v[0] = (__bf16)l0.x; v[1] = (__bf16)l0.y; v[2] = (__bf16)l0.z; v[3] = (__bf16)l0.w;
        v[4] = (__bf16)l1.x; v[5] = (__bf16)l1.y; v[6] = (__bf16)l1.z; v[7] = (__bf16)l1.w;
    }
    ((bf16_8*)pad_in)[t] = v;
}

// ---------------------------------------------------------------------------
// 6b) Conv 3x3 MFMA, oc-split for occupancy: grid (y, oc-half, n), 720 blocks.
// ---------------------------------------------------------------------------
__global__ void __launch_bounds__(256) conv_mfma(
    const __bf16* __restrict__ pad_in,   // (N,47,68,256)
    const __bf16* __restrict__ w_frag,   // fragment-ordered weights
    const float* __restrict__ bias,
    float* __restrict__ out) {           // (N,128,45,60)
    __shared__ __bf16 alds[3 * 66 * 32];         // [dy][px 0..65][ic 0..31]
    int y = blockIdx.x;
    int oh = blockIdx.y;
    int n = blockIdx.z;
    int tid = threadIdx.x;
    int wave = tid >> 6, lane = tid & 63;
    int wm = wave & 1, wq = wave >> 1;
    int quad = lane >> 4, lm = lane & 15;

    f32x4 acc[2][2] = {};
    const bf16_8* wf = (const bf16_8*)w_frag;

    for (int icc = 0; icc < 8; ++icc) {
        __syncthreads();
        for (int t = tid; t < 792; t += 256) {   // 3*66*4 x 16B
            int cq = t & 3;
            int xp = (t >> 2) % 66;
            int dy = (t >> 2) / 66;
            size_t src = (((size_t)n * 47 + (y + dy)) * 68 + xp) * 256 + icc * 32 + cq * 8;
            *(bf16_8*)&alds[(dy * 66 + xp) * 32 + cq * 8] = *(const bf16_8*)&pad_in[src];
        }
        __syncthreads();
        #pragma unroll
        for (int tap = 0; tap < 9; ++tap) {
            int ky = tap / 3, kx = tap % 3;
            bf16_8 b[2], a[2];
            #pragma unroll
            for (int nt = 0; nt < 2; ++nt)
                b[nt] = wf[(((tap * 8 + icc) * 8) + (oh * 4 + wq * 2 + nt)) * 64 + lane];
            #pragma unroll
            for (int mt = 0; mt < 2; ++mt)
                a[mt] = *(const bf16_8*)&alds[(ky * 66 + (wm * 32 + mt * 16 + lm + kx)) * 32 + quad * 8];
            #pragma unroll
            for (int mt = 0; mt < 2; ++mt)
                #pragma unroll
                for (int nt = 0; nt < 2; ++nt)
                    acc[mt][nt] = __builtin_amdgcn_mfma_f32_16x16x32_bf16(
                        a[mt], b[nt], acc[mt][nt], 0, 0, 0);
        }
    }
    #pragma unroll
    for (int mt = 0; mt < 2; ++mt) {
        int x0 = wm * 32 + mt * 16 + quad * 4;
        if (x0 >= WW) continue;
        #pragma unroll
        for (int nt = 0; nt < 2; ++nt) {
            int oc = (oh * 4 + wq * 2 + nt) * 16 + lm;
            float bb = bias[oc];
            f32x4 v = acc[mt][nt];
            v[0] += bb; v[1] += bb; v[2] += bb; v[3] += bb;
            *(f32x4*)&out[(((size_t)n * 128 + oc) * HH + y) * WW + x0] = v;
        }
    }
}

// ---------------------------------------------------------------------------
extern "C" void kernel_launch(void* const* d_in, const int* in_sizes, int n_in,
                              void* d_out, int out_size, void* d_ws, size_t ws_size,
                              hipStream_t stream) {
    const float* cnn    = (const float*)d_in[0];
    const float* orig   = (const float*)d_in[1];
    const float* xy     = (const float*)d_in[2];
    const float* g_w0   = (const float*)d_in[3];
    const float* g_b0   = (const float*)d_in[4];
    const float* g_a0   = (const float*)d_in[5];
    const float* g_w1   = (const float*)d_in[6];
    const float* g_b1   = (const float*)d_in[7];
    const float* g_a1   = (const float*)d_in[8];
    const float* q_w    = (const float*)d_in[9];
    const float* q_b    = (const float*)d_in[10];
    const float* q_a    = (const float*)d_in[11];
    const float* conv_w = (const float*)d_in[12];
    const float* conv_b = (const float*)d_in[13];
    float* out = (float*)d_out;

    float* ws = (float*)d_ws;
    const size_t S = (size_t)MROWS * CC;        // 2,764,800
    float*  cnn_cl = ws;                        // [0, S)
    float*  h      = ws + S;                    // [S, 2S)
    float*  base   = ws + 2 * S;
    __bf16* tgb    = (__bf16*)base;             // MROWS*128 bf16 = 1,382,400 fl
    float*  proj   = base + 1382400;            // 64,800 fl
    int*    knn_i  = (int*)(base + 1382400 + 64800);          // 345,600 slots
    __bf16* wfb    = (__bf16*)(base + 1382400 + 64800 + 345600);
    __bf16* g0h = wfb;            __bf16* g0l = wfb + 16384;
    __bf16* g1h = wfb + 32768;    __bf16* g1l = wfb + 49152;
    __bf16* qh  = wfb + 65536;    __bf16* ql  = wfb + 98304;  // 131,072 bf16
    __bf16* w_frag = wfb + 131072;                            // 294,912 bf16
    __bf16* pad_in = w_frag + 294912;                         // 6,545,408 bf16

    transpose_cl<<<dim3(85, 4, NB), 256, 0, stream>>>(cnn, cnn_cl);
    median_pool<<<16200, 256, 0, stream>>>(xy, orig, proj);
    knn_kernel<<<dim3(338, NB), 512, 0, stream>>>(proj, knn_i);
    prep_all<<<1408, 256, 0, stream>>>(g_w0, g_w1, q_w, conv_w,
                                       g0h, g0l, g1h, g1l, qh, ql, w_frag);

    // GNN iteration 1 (h = cnn_cl)
    fused_g<<<675, 256, 0, stream>>>(cnn_cl, g0h, g0l, g_b0, g_a0,
                                     g1h, g1l, g_b1, g_a1, tgb);
    fused_q<<<675, 256, 0, stream>>>(cnn_cl, tgb, knn_i, qh, ql, q_b, q_a, h);

    // GNN iteration 2
    fused_g<<<675, 256, 0, stream>>>(h, g0h, g0l, g_b0, g_a0,
                                     g1h, g1l, g_b1, g_a1, tgb);
    fused_q<<<675, 256, 0, stream>>>(h, tgb, knn_i, qh, ql, q_b, q_a, h);

    // Conv epilogue
    pack_input<<<3196, 256, 0, stream>>>(cnn_cl, h, pad_in);
    conv_mfma<<<dim3(HH, 2, NB), 256, 0, stream>>>(pad_in, w_frag, conv_b, out);
}

// Round 9
// 253.981 us; speedup vs baseline: 1.2485x; 1.0643x over previous
//
#include <hip/hip_runtime.h>
#include <cfloat>
#include <cmath>

#define NB 8
#define CC 128
#define HH 45
#define WW 60
#define HWP 2700      // H*W
#define KNN 16
#define H0 360
#define W0 480
#define NT 43         // ceil(2700/64) candidates per lane
#define MROWS 21600   // NB * HWP

typedef __bf16 bf16_8 __attribute__((ext_vector_type(8)));
typedef __bf16 bf16_4 __attribute__((ext_vector_type(4)));
typedef float  f32x4  __attribute__((ext_vector_type(4)));

// ---------------------------------------------------------------------------
// 1) Transpose (N,128,HW) -> channel-last bf16 cnn_b + pad_in ch 0..127
// ---------------------------------------------------------------------------
__global__ void transpose_cl(const float* __restrict__ in, __bf16* __restrict__ cnn_b,
                             __bf16* __restrict__ pad_in) {
    __shared__ float tile[32][33];
    int n = blockIdx.z;
    int c0 = blockIdx.y * 32;
    int p0 = blockIdx.x * 32;
    int tx = threadIdx.x & 31, ty = threadIdx.x >> 5;   // 32 x 8
    #pragma unroll
    for (int r = 0; r < 32; r += 8) {
        int c = c0 + ty + r, p = p0 + tx;
        tile[ty + r][tx] = (p < HWP) ? in[((size_t)n * CC + c) * HWP + p] : 0.f;
    }
    __syncthreads();
    #pragma unroll
    for (int r = 0; r < 32; r += 8) {
        int p = p0 + ty + r, c = c0 + tx;
        if (p < HWP) {
            __bf16 bv = (__bf16)tile[tx][ty + r];
            cnn_b[((size_t)n * HWP + p) * 128 + c] = bv;
            int y = p / WW, x = p % WW;
            pad_in[(((size_t)n * 47 + y + 1) * 68 + (x + 1)) * 256 + c] = bv;
        }
    }
}

// ---------------------------------------------------------------------------
// 2) Median pool 8x8: bitonic sort 64 lanes ascending, lane 31 = lower median
// ---------------------------------------------------------------------------
__global__ void median_pool(const float* __restrict__ xy, const float* __restrict__ orig,
                            float* __restrict__ proj) {
    int w = blockIdx.x * 4 + (threadIdx.x >> 6);
    int lane = threadIdx.x & 63;
    int n = w / (3 * HWP);
    int rem = w % (3 * HWP);
    int c = rem / HWP;
    int b = rem % HWP;
    const float* src = (c < 2) ? (xy + ((size_t)n * 2 + c) * H0 * W0)
                               : (orig + ((size_t)n * 4 + 3) * H0 * W0);
    int by = b / WW, bx = b % WW;
    int r = lane >> 3, col = lane & 7;
    float v = src[(by * 8 + r) * W0 + bx * 8 + col];
    #pragma unroll
    for (int k = 2; k <= 64; k <<= 1) {
        #pragma unroll
        for (int j2 = k >> 1; j2 >= 1; j2 >>= 1) {
            float p = __shfl_xor(v, j2, 64);
            bool dir = (lane & k) == 0;
            bool low = (lane & j2) == 0;
            v = (dir == low) ? fminf(v, p) : fmaxf(v, p);
        }
    }
    if (lane == 31) proj[(size_t)c * (NB * HWP) + (size_t)n * HWP + b] = v;
}

// ---------------------------------------------------------------------------
// 3) KNN — validated round-8 selection; pass B ballot-prefix replaced by
//    LDS atomic-slot compaction (order-free: final (d,idx) sort is
//    order-invariant, survivor SET identical).
// ---------------------------------------------------------------------------
__global__ void __launch_bounds__(512, 6) knn_kernel(const float* __restrict__ proj,
                                                     int* __restrict__ knn) {
#pragma clang fp contract(off)
    __shared__ float4 pts[HWP];                    // (x, y, z, sq) per candidate
    __shared__ int sbufj[8][64];                   // survivor indices per wave
    __shared__ int scnt[8];
    int n = blockIdx.y;
    const float* px = proj + (size_t)n * HWP;
    const float* py = proj + (size_t)NB * HWP + (size_t)n * HWP;
    const float* pz = proj + (size_t)2 * NB * HWP + (size_t)n * HWP;
    for (int t = threadIdx.x; t < HWP; t += 512) {
        float x = px[t], y = py[t], z = pz[t];
        float4 p;
        p.x = x; p.y = y; p.z = z;
        p.w = (x * x + y * y) + z * z;             // mirrors jnp.sum(proj*proj,-1)
        pts[t] = p;
    }
    __syncthreads();

    int wave = threadIdx.x >> 6;
    int lane = threadIdx.x & 63;
    int i = blockIdx.x * 8 + wave;                 // row (338*8 >= 2700)
    if (i >= HWP) return;                          // no syncs after this point
    float4 pi = pts[i];
    float xi = pi.x, yi = pi.y, zi = pi.z, sqi = pi.w;

    // ---- Pass A: squared distances; lane min; packed u16 upper bounds ----
    unsigned int sdp[22];
    float mn = FLT_MAX;
    #pragma unroll
    for (int t = 0; t < NT; ++t) {
        int j = lane + t * 64;
        unsigned int u = 0xFFFFu;
        if (j < HWP) {
            float4 pj = pts[j];
            float r = fmaf(zi, pj.z, fmaf(yi, pj.y, xi * pj.x));
            float s = (sqi + pj.w) - 2.0f * r;
            mn = fminf(mn, s);
            float sc = fmaxf(s, 0.f);
            u = (__float_as_uint(sc) + 0xFFFFu) >> 16;   // >= sc, <= sc*(1+2^-7)
        }
        if (t & 1) sdp[t >> 1] |= (u << 16);
        else       sdp[t >> 1] = u;
    }

    // ---- Bitonic sort the 64 lane minima ascending; M_s = rank 15 ----
    float v = mn;
    #pragma unroll
    for (int k = 2; k <= 64; k <<= 1) {
        #pragma unroll
        for (int j2 = k >> 1; j2 >= 1; j2 >>= 1) {
            float p = __shfl_xor(v, j2, 64);
            bool dir = (lane & k) == 0;
            bool low = (lane & j2) == 0;
            v = (dir == low) ? fminf(v, p) : fmaxf(v, p);
        }
    }
    float M_s = __shfl(v, 15, 64);
    float M_test = (M_s > 0.f) ? (M_s * 1.0000005f + 1e-37f) : 0.0f;
    float M_t2 = M_test * 1.009f;                  // cover u16 round-up slack
    unsigned int M_bits = __float_as_uint(M_t2);

    // ---- Pass B: atomic-slot compaction of survivor indices ----
    if (lane == 0) scnt[wave] = 0;
    #pragma unroll
    for (int t = 0; t < NT; ++t) {
        unsigned int u = (t & 1) ? (sdp[t >> 1] >> 16) : (sdp[t >> 1] & 0xFFFFu);
        bool pred = (u << 16) <= M_bits;           // float cmp via bits (both >= +0)
        if (pred) {
            int slot = atomicAdd(&scnt[wave], 1);
            if (slot < 64) sbufj[wave][slot] = lane + t * 64;
        }
    }
    int cnt = scnt[wave];

    int myj = 0;
    if (cnt >= KNN && cnt <= 64) {
        // ---- exact (d, idx) keys for survivors; 64-wide u64 bitonic sort ----
        unsigned long long key = ~0ull;
        if (lane < cnt) {
            int j = sbufj[wave][lane];
            float4 pj = pts[j];
            float r = fmaf(zi, pj.z, fmaf(yi, pj.y, xi * pj.x));
            float s = (sqi + pj.w) - 2.0f * r;
            float d = sqrtf(fmaxf(s, 0.f));
            key = ((unsigned long long)__float_as_uint(d) << 32) | (unsigned int)j;
        }
        #pragma unroll
        for (int k = 2; k <= 64; k <<= 1) {
            #pragma unroll
            for (int j2 = k >> 1; j2 >= 1; j2 >>= 1) {
                unsigned long long p = __shfl_xor(key, j2, 64);
                bool dir = (lane & k) == 0;
                bool low = (lane & j2) == 0;
                bool keepmin = (dir == low);
                bool pless = p < key;
                key = (pless == keepmin) ? p : key;
            }
        }
        myj = (int)(unsigned int)(key & 0xffffffffull);
    } else {
        // ---- rare fallback: 16 rounds of lex-argmin rescan (low-register) ----
        float lastd = -FLT_MAX; int lastj = -1;
        #pragma unroll 1
        for (int r = 0; r < KNN; ++r) {
            float bd = FLT_MAX; int bj = 0x7fffffff;
            #pragma unroll 1
            for (int t = 0; t < NT; ++t) {
                int j = lane + t * 64;
                if (j < HWP) {
                    float4 pj = pts[j];
                    float rr = fmaf(zi, pj.z, fmaf(yi, pj.y, xi * pj.x));
                    float s = (sqi + pj.w) - 2.0f * rr;
                    float d = sqrtf(fmaxf(s, 0.f));
                    bool gt = (d > lastd) || (d == lastd && j > lastj);
                    bool lt = (d < bd) || (d == bd && j < bj);
                    if (gt && lt) { bd = d; bj = j; }
                }
            }
            float md = bd; int mj = bj;
            #pragma unroll
            for (int off = 32; off >= 1; off >>= 1) {
                float od = __shfl_xor(md, off, 64);
                int oj = __shfl_xor(mj, off, 64);
                if (od < md || (od == md && oj < mj)) { md = od; mj = oj; }
            }
            if (lane == r) myj = mj;
            lastd = md; lastj = mj;
        }
    }
    if (lane < KNN)
        knn[((size_t)n * HWP + i) * KNN + lane] = myj;
}

// ---------------------------------------------------------------------------
// 4) Prep: bf16 MFMA A-fragments for g0/g1/q + conv B-fragments
// ---------------------------------------------------------------------------
template <int K>
__device__ __forceinline__ void wfrag_body(const float* __restrict__ Wt,
                                           __bf16* __restrict__ wf, int bx, int tid) {
    int t = bx * 256 + tid;
    int j = t & 7;
    int lane = (t >> 3) & 63;
    int nt = (t >> 9) & 7;
    int kc = t >> 12;
    int oc = nt * 16 + (lane & 15);
    int k = kc * 32 + (lane >> 4) * 8 + j;
    wf[t] = (__bf16)Wt[(size_t)oc * K + k];
}

__global__ void prep_all(const float* __restrict__ g_w0, const float* __restrict__ g_w1,
                         const float* __restrict__ q_w, const float* __restrict__ conv_w,
                         __bf16* __restrict__ g0f, __bf16* __restrict__ g1f,
                         __bf16* __restrict__ qf, __bf16* __restrict__ w_frag) {
    int bx = blockIdx.x, tid = threadIdx.x;
    if (bx < 64)        wfrag_body<128>(g_w0, g0f, bx, tid);
    else if (bx < 128)  wfrag_body<128>(g_w1, g1f, bx - 64, tid);
    else if (bx < 256)  wfrag_body<256>(q_w, qf, bx - 128, tid);
    else {
        int t = (bx - 256) * 256 + tid;              // 294,912
        int j = t & 7;
        int lane = (t >> 3) & 63;
        int ntile = (t >> 9) & 7;
        int icc = (t >> 12) & 7;
        int tap = t >> 15;
        int oc = ntile * 16 + (lane & 15);
        int ic = icc * 32 + (lane >> 4) * 8 + j;
        w_frag[t] = (__bf16)conv_w[((size_t)oc * 256 + ic) * 9 + tap];
    }
}

// ---------------------------------------------------------------------------
// 5) bf16 GEMM layer: 32 px x 128 oc. A = weight fragments (global, L2),
//    B = activations from LDS [pix][136] bf16. 4 MFMA per kc per wave.
// ---------------------------------------------------------------------------
__device__ __forceinline__ void layer_b(
    const __bf16* __restrict__ src,                // LDS [32][136] bf16
    const __bf16* __restrict__ wf,                 // global fragments
    int wave, int lane, int kc_base, f32x4 acc[2][2]) {
    int quad = lane >> 4, lm = lane & 15;
    const bf16_8* wf8 = (const bf16_8*)wf;
    #pragma unroll
    for (int kc = 0; kc < 4; ++kc) {
        bf16_8 b[2], a[2];
        #pragma unroll
        for (int nt = 0; nt < 2; ++nt)
            b[nt] = *(const bf16_8*)&src[(nt * 16 + lm) * 136 + kc * 32 + quad * 8];
        #pragma unroll
        for (int mt = 0; mt < 2; ++mt)
            a[mt] = wf8[((size_t)(kc_base + kc) * 8 + (wave * 2 + mt)) * 64 + lane];
        #pragma unroll
        for (int mt = 0; mt < 2; ++mt)
            #pragma unroll
            for (int nt = 0; nt < 2; ++nt)
                acc[mt][nt] = __builtin_amdgcn_mfma_f32_16x16x32_bf16(
                    a[mt], b[nt], acc[mt][nt], 0, 0, 0);
    }
}

// ---------------------------------------------------------------------------
// 5a) Fused g-MLP: tgb = prelu(g1(prelu(g0(A)))), all bf16
// ---------------------------------------------------------------------------
__global__ void __launch_bounds__(256) fused_g(
    const __bf16* __restrict__ Ain,
    const __bf16* __restrict__ w0f, const float* __restrict__ b0, const float* __restrict__ a0p,
    const __bf16* __restrict__ w1f, const float* __restrict__ b1, const float* __restrict__ a1p,
    __bf16* __restrict__ tgb) {
    __shared__ __bf16 albuf[32 * 136];
    __shared__ __bf16 inter[32 * 136];
    int r0 = blockIdx.x * 32;
    int tid = threadIdx.x;
    int wave = tid >> 6, lane = tid & 63;
    int quad = lane >> 4, lm = lane & 15;
    #pragma unroll
    for (int t = tid; t < 512; t += 256) {
        int row = t >> 4, c8 = (t & 15) * 8;
        *(bf16_8*)&albuf[row * 136 + c8] =
            *(const bf16_8*)&Ain[(size_t)(r0 + row) * 128 + c8];
    }
    __syncthreads();
    // layer 0
    {
        f32x4 acc[2][2] = {};
        layer_b(albuf, w0f, wave, lane, 0, acc);
        float alpha = a0p[0];
        #pragma unroll
        for (int mt = 0; mt < 2; ++mt) {
            int oc0 = wave * 32 + mt * 16 + quad * 4;
            float4 bb = *(const float4*)&b0[oc0];
            float bv[4] = {bb.x, bb.y, bb.z, bb.w};
            #pragma unroll
            for (int nt = 0; nt < 2; ++nt) {
                bf16_4 o;
                #pragma unroll
                for (int reg = 0; reg < 4; ++reg) {
                    float vv = acc[mt][nt][reg] + bv[reg];
                    vv = (vv >= 0.f) ? vv : alpha * vv;
                    o[reg] = (__bf16)vv;
                }
                *(bf16_4*)&inter[(nt * 16 + lm) * 136 + oc0] = o;
            }
        }
    }
    __syncthreads();
    // layer 1
    {
        f32x4 acc[2][2] = {};
        layer_b(inter, w1f, wave, lane, 0, acc);
        float alpha = a1p[0];
        #pragma unroll
        for (int mt = 0; mt < 2; ++mt) {
            int oc0 = wave * 32 + mt * 16 + quad * 4;
            float4 bb = *(const float4*)&b1[oc0];
            float bv[4] = {bb.x, bb.y, bb.z, bb.w};
            #pragma unroll
            for (int nt = 0; nt < 2; ++nt) {
                bf16_4 o;
                #pragma unroll
                for (int reg = 0; reg < 4; ++reg) {
                    float vv = acc[mt][nt][reg] + bv[reg];
                    vv = (vv >= 0.f) ? vv : alpha * vv;
                    o[reg] = (__bf16)vv;
                }
                *(bf16_4*)&tgb[(size_t)(r0 + nt * 16 + lm) * 128 + oc0] = o;
            }
        }
    }
}

// ---------------------------------------------------------------------------
// 5b) Fused gather-mean + q-GEMM. mode 0: write bf16 linear (h_b).
//     mode 1: scatter bf16 into pad_in channels 128..255 (conv staging).
// ---------------------------------------------------------------------------
__global__ void __launch_bounds__(256) fused_q(
    const __bf16* __restrict__ Ain, const __bf16* __restrict__ tgb,
    const int* __restrict__ knn_idx,
    const __bf16* __restrict__ qf, const float* __restrict__ qb,
    const float* __restrict__ qap,
    __bf16* __restrict__ out_lin, __bf16* __restrict__ pad_out, int mode) {
    __shared__ __bf16 hlds[32 * 136];
    __shared__ __bf16 mlds[32 * 136];
    int r0 = blockIdx.x * 32;
    int tid = threadIdx.x;
    int wave = tid >> 6, lane = tid & 63;
    int quad = lane >> 4, lm = lane & 15;
    #pragma unroll
    for (int t = tid; t < 512; t += 256) {
        int row = t >> 4, c8 = (t & 15) * 8;
        *(bf16_8*)&hlds[row * 136 + c8] =
            *(const bf16_8*)&Ain[(size_t)(r0 + row) * 128 + c8];
    }
    {   // gather + mean: thread handles (pix, 16 channels)
        int pix = tid >> 3;
        int oct0 = (tid & 7) * 2;
        int grow = r0 + pix;
        int nimg = grow / HWP;
        const int* kn = knn_idx + (size_t)grow * KNN;
        const __bf16* tbase = tgb + ((size_t)nimg * HWP) * 128;
        float a0[8] = {}, a1[8] = {};
        #pragma unroll
        for (int k = 0; k < KNN; ++k) {
            int j = kn[k];
            const __bf16* srcp = tbase + (size_t)j * 128 + oct0 * 8;
            bf16_8 v0 = *(const bf16_8*)srcp;
            bf16_8 v1 = *(const bf16_8*)(srcp + 8);
            #pragma unroll
            for (int e = 0; e < 8; ++e) { a0[e] += (float)v0[e]; a1[e] += (float)v1[e]; }
        }
        const float s = 1.f / 16.f;
        bf16_8 o0, o1;
        #pragma unroll
        for (int e = 0; e < 8; ++e) { o0[e] = (__bf16)(a0[e] * s); o1[e] = (__bf16)(a1[e] * s); }
        *(bf16_8*)&mlds[pix * 136 + oct0 * 8] = o0;
        *(bf16_8*)&mlds[pix * 136 + oct0 * 8 + 8] = o1;
    }
    __syncthreads();
    f32x4 acc[2][2] = {};
    layer_b(hlds, qf, wave, lane, 0, acc);   // k 0..127 (h part)
    layer_b(mlds, qf, wave, lane, 4, acc);   // k 128..255 (m part)
    float alpha = qap[0];
    #pragma unroll
    for (int mt = 0; mt < 2; ++mt) {
        int oc0 = wave * 32 + mt * 16 + quad * 4;
        float4 bb = *(const float4*)&qb[oc0];
        float bv[4] = {bb.x, bb.y, bb.z, bb.w};
        #pragma unroll
        for (int nt = 0; nt < 2; ++nt) {
            bf16_4 o;
            #pragma unroll
            for (int reg = 0; reg < 4; ++reg) {
                float vv = acc[mt][nt][reg] + bv[reg];
                vv = (vv >= 0.f) ? vv : alpha * vv;
                o[reg] = (__bf16)vv;
            }
            int grow = r0 + nt * 16 + lm;
            if (mode == 0) {
                *(bf16_4*)&out_lin[(size_t)grow * 128 + oc0] = o;
            } else {
                int n = grow / HWP, p = grow % HWP;
                int y = p / WW, x = p % WW;
                *(bf16_4*)&pad_out[(((size_t)n * 47 + y + 1) * 68 + (x + 1)) * 256 + 128 + oc0] = o;
            }
        }
    }
}

// ---------------------------------------------------------------------------
// 6a) Zero the 496 halo cells per image in pad_in (all 256 channels)
// ---------------------------------------------------------------------------
__global__ void zero_border(__bf16* __restrict__ pad_in) {
    int t = blockIdx.x * 256 + threadIdx.x;      // 496 cells x 8 img x 32 grp
    int cg = t & 31;
    int s = t >> 5;
    int cell = s % 496;
    int n = s / 496;
    int y, x;
    if (cell < 136) { y = (cell < 68) ? 0 : 46; x = cell % 68; }
    else {
        int rem = cell - 136;
        y = 1 + rem / 8;
        int k = rem % 8;
        x = (k == 0) ? 0 : (60 + k);
    }
    bf16_8 z = {};
    *(bf16_8*)&pad_in[(((size_t)n * 47 + y) * 68 + x) * 256 + cg * 8] = z;
}

// ---------------------------------------------------------------------------
// 6b) Conv 3x3 MFMA (validated round 8)
// ---------------------------------------------------------------------------
__global__ void __launch_bounds__(256) conv_mfma(
    const __bf16* __restrict__ pad_in,   // (N,47,68,256)
    const __bf16* __restrict__ w_frag,   // fragment-ordered weights
    const float* __restrict__ bias,
    float* __restrict__ out) {           // (N,128,45,60)
    __shared__ __bf16 alds[3 * 66 * 32];         // [dy][px 0..65][ic 0..31]
    int y = blockIdx.x;
    int oh = blockIdx.y;
    int n = blockIdx.z;
    int tid = threadIdx.x;
    int wave = tid >> 6, lane = tid & 63;
    int wm = wave & 1, wq = wave >> 1;
    int quad = lane >> 4, lm = lane & 15;

    f32x4 acc[2][2] = {};
    const bf16_8* wf = (const bf16_8*)w_frag;

    for (int icc = 0; icc < 8; ++icc) {
        __syncthreads();
        for (int t = tid; t < 792; t += 256) {   // 3*66*4 x 16B
            int cq = t & 3;
            int xp = (t >> 2) % 66;
            int dy = (t >> 2) / 66;
            size_t src = (((size_t)n * 47 + (y + dy)) * 68 + xp) * 256 + icc * 32 + cq * 8;
            *(bf16_8*)&alds[(dy * 66 + xp) * 32 + cq * 8] = *(const bf16_8*)&pad_in[src];
        }
        __syncthreads();
        #pragma unroll
        for (int tap = 0; tap < 9; ++tap) {
            int ky = tap / 3, kx = tap % 3;
            bf16_8 b[2], a[2];
            #pragma unroll
            for (int nt = 0; nt < 2; ++nt)
                b[nt] = wf[(((tap * 8 + icc) * 8) + (oh * 4 + wq * 2 + nt)) * 64 + lane];
            #pragma unroll
            for (int mt = 0; mt < 2; ++mt)
                a[mt] = *(const bf16_8*)&alds[(ky * 66 + (wm * 32 + mt * 16 + lm + kx)) * 32 + quad * 8];
            #pragma unroll
            for (int mt = 0; mt < 2; ++mt)
                #pragma unroll
                for (int nt = 0; nt < 2; ++nt)
                    acc[mt][nt] = __builtin_amdgcn_mfma_f32_16x16x32_bf16(
                        a[mt], b[nt], acc[mt][nt], 0, 0, 0);
        }
    }
    #pragma unroll
    for (int mt = 0; mt < 2; ++mt) {
        int x0 = wm * 32 + mt * 16 + quad * 4;
        if (x0 >= WW) continue;
        #pragma unroll
        for (int nt = 0; nt < 2; ++nt) {
            int oc = (oh * 4 + wq * 2 + nt) * 16 + lm;
            float bb = bias[oc];
            f32x4 v = acc[mt][nt];
            v[0] += bb; v[1] += bb; v[2] += bb; v[3] += bb;
            *(f32x4*)&out[(((size_t)n * 128 + oc) * HH + y) * WW + x0] = v;
        }
    }
}

// ---------------------------------------------------------------------------
extern "C" void kernel_launch(void* const* d_in, const int* in_sizes, int n_in,
                              void* d_out, int out_size, void* d_ws, size_t ws_size,
                              hipStream_t stream) {
    const float* cnn    = (const float*)d_in[0];
    const float* orig   = (const float*)d_in[1];
    const float* xy     = (const float*)d_in[2];
    const float* g_w0   = (const float*)d_in[3];
    const float* g_b0   = (const float*)d_in[4];
    const float* g_a0   = (const float*)d_in[5];
    const float* g_w1   = (const float*)d_in[6];
    const float* g_b1   = (const float*)d_in[7];
    const float* g_a1   = (const float*)d_in[8];
    const float* q_w    = (const float*)d_in[9];
    const float* q_b    = (const float*)d_in[10];
    const float* q_a    = (const float*)d_in[11];
    const float* conv_w = (const float*)d_in[12];
    const float* conv_b = (const float*)d_in[13];
    float* out = (float*)d_out;

    float* ws = (float*)d_ws;
    const size_t SB = (size_t)MROWS * 128;      // bf16 activation plane count
    __bf16* cnn_b  = (__bf16*)ws;               // SB bf16
    __bf16* h_b    = cnn_b + SB;
    __bf16* tgb    = h_b + SB;
    float*  proj   = (float*)(tgb + SB);        // 64,800 fl
    int*    knn_i  = (int*)(proj + 64800);      // 345,600 int
    __bf16* g0f    = (__bf16*)(knn_i + (size_t)MROWS * KNN);
    __bf16* g1f    = g0f + 16384;
    __bf16* qf     = g1f + 16384;               // 32,768 bf16
    __bf16* w_frag = qf + 32768;                // 294,912 bf16
    __bf16* pad_in = w_frag + 294912;           // 6,545,408 bf16

    transpose_cl<<<dim3(85, 4, NB), 256, 0, stream>>>(cnn, cnn_b, pad_in);
    median_pool<<<16200, 256, 0, stream>>>(xy, orig, proj);
    knn_kernel<<<dim3(338, NB), 512, 0, stream>>>(proj, knn_i);
    prep_all<<<1408, 256, 0, stream>>>(g_w0, g_w1, q_w, conv_w, g0f, g1f, qf, w_frag);
    zero_border<<<496, 256, 0, stream>>>(pad_in);

    // GNN iteration 1
    fused_g<<<675, 256, 0, stream>>>(cnn_b, g0f, g_b0, g_a0, g1f, g_b1, g_a1, tgb);
    fused_q<<<675, 256, 0, stream>>>(cnn_b, tgb, knn_i, qf, q_b, q_a, h_b, pad_in, 0);

    // GNN iteration 2 (second fused_q scatters straight into conv staging)
    fused_g<<<675, 256, 0, stream>>>(h_b, g0f, g_b0, g_a0, g1f, g_b1, g_a1, tgb);
    fused_q<<<675, 256, 0, stream>>>(h_b, tgb, knn_i, qf, q_b, q_a, h_b, pad_in, 1);

    // Conv epilogue
    conv_mfma<<<dim3(HH, 2, NB), 256, 0, stream>>>(pad_in, w_frag, conv_b, out);
}

// Round 10
// 244.131 us; speedup vs baseline: 1.2989x; 1.0403x over previous
//
#include <hip/hip_runtime.h>
#include <cfloat>
#include <cmath>

#define NB 8
#define CC 128
#define HH 45
#define WW 60
#define HWP 2700      // H*W
#define KNN 16
#define H0 360
#define W0 480
#define NT 43         // ceil(2700/64) candidates per lane
#define MROWS 21600   // NB * HWP

typedef __bf16 bf16_8 __attribute__((ext_vector_type(8)));
typedef __bf16 bf16_4 __attribute__((ext_vector_type(4)));
typedef float  f32x4  __attribute__((ext_vector_type(4)));

// ---------------------------------------------------------------------------
// 0) Fused setup: transpose+bf16-cast (2720 blk) | median pool (16200 blk) |
//    weight fragment prep (1408 blk) | pad halo zero (496 blk)
// ---------------------------------------------------------------------------
template <int K>
__device__ __forceinline__ void wfrag_body(const float* __restrict__ Wt,
                                           __bf16* __restrict__ wf, int bx, int tid) {
    int t = bx * 256 + tid;
    int j = t & 7;
    int lane = (t >> 3) & 63;
    int nt = (t >> 9) & 7;
    int kc = t >> 12;
    int oc = nt * 16 + (lane & 15);
    int k = kc * 32 + (lane >> 4) * 8 + j;
    wf[t] = (__bf16)Wt[(size_t)oc * K + k];
}

__global__ void __launch_bounds__(256) setup_all(
    const float* __restrict__ cnn, const float* __restrict__ xy,
    const float* __restrict__ orig,
    const float* __restrict__ g_w0, const float* __restrict__ g_w1,
    const float* __restrict__ q_w, const float* __restrict__ conv_w,
    __bf16* __restrict__ cnn_b, __bf16* __restrict__ pad_in,
    float* __restrict__ proj,
    __bf16* __restrict__ g0f, __bf16* __restrict__ g1f,
    __bf16* __restrict__ qf, __bf16* __restrict__ w_frag) {
    int bx = blockIdx.x;
    int tid = threadIdx.x;
    if (bx < 2720) {
        // ---- transpose (N,128,HW) -> cnn_b + pad_in ch 0..127 ----
        __shared__ float tile[32][33];
        int n = bx / 340;
        int r2 = bx % 340;
        int c0 = (r2 / 85) * 32;
        int p0 = (r2 % 85) * 32;
        int tx = tid & 31, ty = tid >> 5;
        #pragma unroll
        for (int r = 0; r < 32; r += 8) {
            int c = c0 + ty + r, p = p0 + tx;
            tile[ty + r][tx] = (p < HWP) ? cnn[((size_t)n * CC + c) * HWP + p] : 0.f;
        }
        __syncthreads();
        #pragma unroll
        for (int r = 0; r < 32; r += 8) {
            int p = p0 + ty + r, c = c0 + tx;
            if (p < HWP) {
                __bf16 bv = (__bf16)tile[tx][ty + r];
                cnn_b[((size_t)n * HWP + p) * 128 + c] = bv;
                int y = p / WW, x = p % WW;
                pad_in[(((size_t)n * 47 + y + 1) * 68 + (x + 1)) * 256 + c] = bv;
            }
        }
    } else if (bx < 2720 + 16200) {
        // ---- median pool 8x8: bitonic sort, lane 31 = lower median ----
        int w = (bx - 2720) * 4 + (tid >> 6);
        int lane = tid & 63;
        int n = w / (3 * HWP);
        int rem = w % (3 * HWP);
        int c = rem / HWP;
        int b = rem % HWP;
        const float* src = (c < 2) ? (xy + ((size_t)n * 2 + c) * H0 * W0)
                                   : (orig + ((size_t)n * 4 + 3) * H0 * W0);
        int by = b / WW, bxp = b % WW;
        int r = lane >> 3, col = lane & 7;
        float v = src[(by * 8 + r) * W0 + bxp * 8 + col];
        #pragma unroll
        for (int k = 2; k <= 64; k <<= 1) {
            #pragma unroll
            for (int j2 = k >> 1; j2 >= 1; j2 >>= 1) {
                float p = __shfl_xor(v, j2, 64);
                bool dir = (lane & k) == 0;
                bool low = (lane & j2) == 0;
                v = (dir == low) ? fminf(v, p) : fmaxf(v, p);
            }
        }
        if (lane == 31) proj[(size_t)c * (NB * HWP) + (size_t)n * HWP + b] = v;
    } else if (bx < 2720 + 16200 + 1408) {
        int pb = bx - (2720 + 16200);
        if (pb < 64)        wfrag_body<128>(g_w0, g0f, pb, tid);
        else if (pb < 128)  wfrag_body<128>(g_w1, g1f, pb - 64, tid);
        else if (pb < 256)  wfrag_body<256>(q_w, qf, pb - 128, tid);
        else {
            int t = (pb - 256) * 256 + tid;          // 294,912
            int j = t & 7;
            int lane = (t >> 3) & 63;
            int ntile = (t >> 9) & 7;
            int icc = (t >> 12) & 7;
            int tap = t >> 15;
            int oc = ntile * 16 + (lane & 15);
            int ic = icc * 32 + (lane >> 4) * 8 + j;
            w_frag[t] = (__bf16)conv_w[((size_t)oc * 256 + ic) * 9 + tap];
        }
    } else {
        // ---- zero 496 halo cells per image (all 256 ch) ----
        int t = (bx - (2720 + 16200 + 1408)) * 256 + tid;
        int cg = t & 31;
        int s = t >> 5;
        int cell = s % 496;
        int n = s / 496;
        int y, x;
        if (cell < 136) { y = (cell < 68) ? 0 : 46; x = cell % 68; }
        else {
            int rem = cell - 136;
            y = 1 + rem / 8;
            int k = rem % 8;
            x = (k == 0) ? 0 : (60 + k);
        }
        bf16_8 z = {};
        *(bf16_8*)&pad_in[(((size_t)n * 47 + y) * 68 + x) * 256 + cg * 8] = z;
    }
}

// ---------------------------------------------------------------------------
// 3) KNN — validated round-9 algorithm; u16-domain threshold compare.
// ---------------------------------------------------------------------------
__global__ void __launch_bounds__(512, 6) knn_kernel(const float* __restrict__ proj,
                                                     int* __restrict__ knn) {
#pragma clang fp contract(off)
    __shared__ float4 pts[HWP];                    // (x, y, z, sq) per candidate
    __shared__ int sbufj[8][64];                   // survivor indices per wave
    __shared__ int scnt[8];
    int n = blockIdx.y;
    const float* px = proj + (size_t)n * HWP;
    const float* py = proj + (size_t)NB * HWP + (size_t)n * HWP;
    const float* pz = proj + (size_t)2 * NB * HWP + (size_t)n * HWP;
    for (int t = threadIdx.x; t < HWP; t += 512) {
        float x = px[t], y = py[t], z = pz[t];
        float4 p;
        p.x = x; p.y = y; p.z = z;
        p.w = (x * x + y * y) + z * z;             // mirrors jnp.sum(proj*proj,-1)
        pts[t] = p;
    }
    __syncthreads();

    int wave = threadIdx.x >> 6;
    int lane = threadIdx.x & 63;
    int i = blockIdx.x * 8 + wave;                 // row (338*8 >= 2700)
    if (i >= HWP) return;                          // no syncs after this point
    float4 pi = pts[i];
    float xi = pi.x, yi = pi.y, zi = pi.z, sqi = pi.w;

    // ---- Pass A: squared distances; lane min; packed u16 upper bounds ----
    unsigned int sdp[22];
    float mn = FLT_MAX;
    #pragma unroll
    for (int t = 0; t < NT; ++t) {
        int j = lane + t * 64;
        unsigned int u = 0xFFFFu;
        if (j < HWP) {
            float4 pj = pts[j];
            float r = fmaf(zi, pj.z, fmaf(yi, pj.y, xi * pj.x));
            float s = (sqi + pj.w) - 2.0f * r;
            mn = fminf(mn, s);
            float sc = fmaxf(s, 0.f);
            u = (__float_as_uint(sc) + 0xFFFFu) >> 16;   // >= sc, <= sc*(1+2^-7)
        }
        if (t & 1) sdp[t >> 1] |= (u << 16);
        else       sdp[t >> 1] = u;
    }

    // ---- Bitonic sort the 64 lane minima ascending; M_s = rank 15 ----
    float v = mn;
    #pragma unroll
    for (int k = 2; k <= 64; k <<= 1) {
        #pragma unroll
        for (int j2 = k >> 1; j2 >= 1; j2 >>= 1) {
            float p = __shfl_xor(v, j2, 64);
            bool dir = (lane & k) == 0;
            bool low = (lane & j2) == 0;
            v = (dir == low) ? fminf(v, p) : fmaxf(v, p);
        }
    }
    float M_s = __shfl(v, 15, 64);
    float M_test = (M_s > 0.f) ? (M_s * 1.0000005f + 1e-37f) : 0.0f;
    float M_t2 = M_test * 1.009f;                  // cover u16 round-up slack
    unsigned int M16 = __float_as_uint(M_t2) >> 16;   // u<=M16 <=> (u<<16)<=M_bits

    // ---- Pass B: atomic-slot compaction of survivor indices ----
    if (lane == 0) scnt[wave] = 0;
    #pragma unroll
    for (int t = 0; t < NT; ++t) {
        unsigned int u = (t & 1) ? (sdp[t >> 1] >> 16) : (sdp[t >> 1] & 0xFFFFu);
        if (u <= M16) {
            int slot = atomicAdd(&scnt[wave], 1);
            if (slot < 64) sbufj[wave][slot] = lane + t * 64;
        }
    }
    int cnt = scnt[wave];

    int myj = 0;
    if (cnt >= KNN && cnt <= 64) {
        // ---- exact (d, idx) keys for survivors; 64-wide u64 bitonic sort ----
        unsigned long long key = ~0ull;
        if (lane < cnt) {
            int j = sbufj[wave][lane];
            float4 pj = pts[j];
            float r = fmaf(zi, pj.z, fmaf(yi, pj.y, xi * pj.x));
            float s = (sqi + pj.w) - 2.0f * r;
            float d = sqrtf(fmaxf(s, 0.f));
            key = ((unsigned long long)__float_as_uint(d) << 32) | (unsigned int)j;
        }
        #pragma unroll
        for (int k = 2; k <= 64; k <<= 1) {
            #pragma unroll
            for (int j2 = k >> 1; j2 >= 1; j2 >>= 1) {
                unsigned long long p = __shfl_xor(key, j2, 64);
                bool dir = (lane & k) == 0;
                bool low = (lane & j2) == 0;
                bool keepmin = (dir == low);
                bool pless = p < key;
                key = (pless == keepmin) ? p : key;
            }
        }
        myj = (int)(unsigned int)(key & 0xffffffffull);
    } else {
        // ---- rare fallback: 16 rounds of lex-argmin rescan (low-register) ----
        float lastd = -FLT_MAX; int lastj = -1;
        #pragma unroll 1
        for (int r = 0; r < KNN; ++r) {
            float bd = FLT_MAX; int bj = 0x7fffffff;
            #pragma unroll 1
            for (int t = 0; t < NT; ++t) {
                int j = lane + t * 64;
                if (j < HWP) {
                    float4 pj = pts[j];
                    float rr = fmaf(zi, pj.z, fmaf(yi, pj.y, xi * pj.x));
                    float s = (sqi + pj.w) - 2.0f * rr;
                    float d = sqrtf(fmaxf(s, 0.f));
                    bool gt = (d > lastd) || (d == lastd && j > lastj);
                    bool lt = (d < bd) || (d == bd && j < bj);
                    if (gt && lt) { bd = d; bj = j; }
                }
            }
            float md = bd; int mj = bj;
            #pragma unroll
            for (int off = 32; off >= 1; off >>= 1) {
                float od = __shfl_xor(md, off, 64);
                int oj = __shfl_xor(mj, off, 64);
                if (od < md || (od == md && oj < mj)) { md = od; mj = oj; }
            }
            if (lane == r) myj = mj;
            lastd = md; lastj = mj;
        }
    }
    if (lane < KNN)
        knn[((size_t)n * HWP + i) * KNN + lane] = myj;
}

// ---------------------------------------------------------------------------
// 5) bf16 GEMM layer: 32 px x 128 oc. A = weight fragments (global, L2),
//    B = activations from LDS [pix][136] bf16. 4 MFMA per kc per wave.
// ---------------------------------------------------------------------------
__device__ __forceinline__ void layer_b(
    const __bf16* __restrict__ src,                // LDS [32][136] bf16
    const __bf16* __restrict__ wf,                 // global fragments
    int wave, int lane, int kc_base, f32x4 acc[2][2]) {
    int quad = lane >> 4, lm = lane & 15;
    const bf16_8* wf8 = (const bf16_8*)wf;
    #pragma unroll
    for (int kc = 0; kc < 4; ++kc) {
        bf16_8 b[2], a[2];
        #pragma unroll
        for (int nt = 0; nt < 2; ++nt)
            b[nt] = *(const bf16_8*)&src[(nt * 16 + lm) * 136 + kc * 32 + quad * 8];
        #pragma unroll
        for (int mt = 0; mt < 2; ++mt)
            a[mt] = wf8[((size_t)(kc_base + kc) * 8 + (wave * 2 + mt)) * 64 + lane];
        #pragma unroll
        for (int mt = 0; mt < 2; ++mt)
            #pragma unroll
            for (int nt = 0; nt < 2; ++nt)
                acc[mt][nt] = __builtin_amdgcn_mfma_f32_16x16x32_bf16(
                    a[mt], b[nt], acc[mt][nt], 0, 0, 0);
    }
}

// ---------------------------------------------------------------------------
// 5a) Fused g-MLP: tgb = prelu(g1(prelu(g0(A)))), all bf16
// ---------------------------------------------------------------------------
__global__ void __launch_bounds__(256) fused_g(
    const __bf16* __restrict__ Ain,
    const __bf16* __restrict__ w0f, const float* __restrict__ b0, const float* __restrict__ a0p,
    const __bf16* __restrict__ w1f, const float* __restrict__ b1, const float* __restrict__ a1p,
    __bf16* __restrict__ tgb) {
    __shared__ __bf16 albuf[32 * 136];
    __shared__ __bf16 inter[32 * 136];
    int r0 = blockIdx.x * 32;
    int tid = threadIdx.x;
    int wave = tid >> 6, lane = tid & 63;
    int quad = lane >> 4, lm = lane & 15;
    #pragma unroll
    for (int t = tid; t < 512; t += 256) {
        int row = t >> 4, c8 = (t & 15) * 8;
        *(bf16_8*)&albuf[row * 136 + c8] =
            *(const bf16_8*)&Ain[(size_t)(r0 + row) * 128 + c8];
    }
    __syncthreads();
    // layer 0
    {
        f32x4 acc[2][2] = {};
        layer_b(albuf, w0f, wave, lane, 0, acc);
        float alpha = a0p[0];
        #pragma unroll
        for (int mt = 0; mt < 2; ++mt) {
            int oc0 = wave * 32 + mt * 16 + quad * 4;
            float4 bb = *(const float4*)&b0[oc0];
            float bv[4] = {bb.x, bb.y, bb.z, bb.w};
            #pragma unroll
            for (int nt = 0; nt < 2; ++nt) {
                bf16_4 o;
                #pragma unroll
                for (int reg = 0; reg < 4; ++reg) {
                    float vv = acc[mt][nt][reg] + bv[reg];
                    vv = (vv >= 0.f) ? vv : alpha * vv;
                    o[reg] = (__bf16)vv;
                }
                *(bf16_4*)&inter[(nt * 16 + lm) * 136 + oc0] = o;
            }
        }
    }
    __syncthreads();
    // layer 1
    {
        f32x4 acc[2][2] = {};
        layer_b(inter, w1f, wave, lane, 0, acc);
        float alpha = a1p[0];
        #pragma unroll
        for (int mt = 0; mt < 2; ++mt) {
            int oc0 = wave * 32 + mt * 16 + quad * 4;
            float4 bb = *(const float4*)&b1[oc0];
            float bv[4] = {bb.x, bb.y, bb.z, bb.w};
            #pragma unroll
            for (int nt = 0; nt < 2; ++nt) {
                bf16_4 o;
                #pragma unroll
                for (int reg = 0; reg < 4; ++reg) {
                    float vv = acc[mt][nt][reg] + bv[reg];
                    vv = (vv >= 0.f) ? vv : alpha * vv;
                    o[reg] = (__bf16)vv;
                }
                *(bf16_4*)&tgb[(size_t)(r0 + nt * 16 + lm) * 128 + oc0] = o;
            }
        }
    }
}

// ---------------------------------------------------------------------------
// 5b) Fused gather-mean + q-GEMM. mode 0: write bf16 linear (h_b).
//     mode 1: scatter bf16 into pad_in channels 128..255 (conv staging).
// ---------------------------------------------------------------------------
__global__ void __launch_bounds__(256) fused_q(
    const __bf16* __restrict__ Ain, const __bf16* __restrict__ tgb,
    const int* __restrict__ knn_idx,
    const __bf16* __restrict__ qf, const float* __restrict__ qb,
    const float* __restrict__ qap,
    __bf16* __restrict__ out_lin, __bf16* __restrict__ pad_out, int mode) {
    __shared__ __bf16 hlds[32 * 136];
    __shared__ __bf16 mlds[32 * 136];
    int r0 = blockIdx.x * 32;
    int tid = threadIdx.x;
    int wave = tid >> 6, lane = tid & 63;
    int quad = lane >> 4, lm = lane & 15;
    #pragma unroll
    for (int t = tid; t < 512; t += 256) {
        int row = t >> 4, c8 = (t & 15) * 8;
        *(bf16_8*)&hlds[row * 136 + c8] =
            *(const bf16_8*)&Ain[(size_t)(r0 + row) * 128 + c8];
    }
    {   // gather + mean: thread handles (pix, 16 channels)
        int pix = tid >> 3;
        int oct0 = (tid & 7) * 2;
        int grow = r0 + pix;
        int nimg = grow / HWP;
        const int* kn = knn_idx + (size_t)grow * KNN;
        const __bf16* tbase = tgb + ((size_t)nimg * HWP) * 128;
        float a0[8] = {}, a1[8] = {};
        #pragma unroll
        for (int k = 0; k < KNN; ++k) {
            int j = kn[k];
            const __bf16* srcp = tbase + (size_t)j * 128 + oct0 * 8;
            bf16_8 v0 = *(const bf16_8*)srcp;
            bf16_8 v1 = *(const bf16_8*)(srcp + 8);
            #pragma unroll
            for (int e = 0; e < 8; ++e) { a0[e] += (float)v0[e]; a1[e] += (float)v1[e]; }
        }
        const float s = 1.f / 16.f;
        bf16_8 o0, o1;
        #pragma unroll
        for (int e = 0; e < 8; ++e) { o0[e] = (__bf16)(a0[e] * s); o1[e] = (__bf16)(a1[e] * s); }
        *(bf16_8*)&mlds[pix * 136 + oct0 * 8] = o0;
        *(bf16_8*)&mlds[pix * 136 + oct0 * 8 + 8] = o1;
    }
    __syncthreads();
    f32x4 acc[2][2] = {};
    layer_b(hlds, qf, wave, lane, 0, acc);   // k 0..127 (h part)
    layer_b(mlds, qf, wave, lane, 4, acc);   // k 128..255 (m part)
    float alpha = qap[0];
    #pragma unroll
    for (int mt = 0; mt < 2; ++mt) {
        int oc0 = wave * 32 + mt * 16 + quad * 4;
        float4 bb = *(const float4*)&qb[oc0];
        float bv[4] = {bb.x, bb.y, bb.z, bb.w};
        #pragma unroll
        for (int nt = 0; nt < 2; ++nt) {
            bf16_4 o;
            #pragma unroll
            for (int reg = 0; reg < 4; ++reg) {
                float vv = acc[mt][nt][reg] + bv[reg];
                vv = (vv >= 0.f) ? vv : alpha * vv;
                o[reg] = (__bf16)vv;
            }
            int grow = r0 + nt * 16 + lm;
            if (mode == 0) {
                *(bf16_4*)&out_lin[(size_t)grow * 128 + oc0] = o;
            } else {
                int n = grow / HWP, p = grow % HWP;
                int y = p / WW, x = p % WW;
                *(bf16_4*)&pad_out[(((size_t)n * 47 + y + 1) * 68 + (x + 1)) * 256 + 128 + oc0] = o;
            }
        }
    }
}

// ---------------------------------------------------------------------------
// 6) Conv 3x3 MFMA: 64-ch ic-chunks (4 barrier iters) + LDS row stride 72
//    (2-way banks instead of the old 8-way conflict at stride 32).
// ---------------------------------------------------------------------------
__global__ void __launch_bounds__(256) conv_mfma(
    const __bf16* __restrict__ pad_in,   // (N,47,68,256)
    const __bf16* __restrict__ w_frag,   // fragment-ordered weights
    const float* __restrict__ bias,
    float* __restrict__ out) {           // (N,128,45,60)
    __shared__ __bf16 alds[3 * 66 * 72];         // [dy][px 0..65][ic 0..63], stride 72
    int y = blockIdx.x;
    int oh = blockIdx.y;
    int n = blockIdx.z;
    int tid = threadIdx.x;
    int wave = tid >> 6, lane = tid & 63;
    int wm = wave & 1, wq = wave >> 1;
    int quad = lane >> 4, lm = lane & 15;

    f32x4 acc[2][2] = {};
    const bf16_8* wf = (const bf16_8*)w_frag;

    for (int c64 = 0; c64 < 4; ++c64) {
        __syncthreads();
        for (int t = tid; t < 1584; t += 256) {  // 3*66*8 x 16B
            int cq = t & 7;
            int xp = (t >> 3) % 66;
            int dy = (t >> 3) / 66;
            size_t src = (((size_t)n * 47 + (y + dy)) * 68 + xp) * 256 + c64 * 64 + cq * 8;
            *(bf16_8*)&alds[(dy * 66 + xp) * 72 + cq * 8] = *(const bf16_8*)&pad_in[src];
        }
        __syncthreads();
        #pragma unroll
        for (int tap = 0; tap < 9; ++tap) {
            int ky = tap / 3, kx = tap % 3;
            #pragma unroll
            for (int h = 0; h < 2; ++h) {
                int icc = c64 * 2 + h;
                bf16_8 b[2], a[2];
                #pragma unroll
                for (int nt = 0; nt < 2; ++nt)
                    b[nt] = wf[(((tap * 8 + icc) * 8) + (oh * 4 + wq * 2 + nt)) * 64 + lane];
                #pragma unroll
                for (int mt = 0; mt < 2; ++mt)
                    a[mt] = *(const bf16_8*)&alds[(ky * 66 + (wm * 32 + mt * 16 + lm + kx)) * 72
                                                  + h * 32 + quad * 8];
                #pragma unroll
                for (int mt = 0; mt < 2; ++mt)
                    #pragma unroll
                    for (int nt = 0; nt < 2; ++nt)
                        acc[mt][nt] = __builtin_amdgcn_mfma_f32_16x16x32_bf16(
                            a[mt], b[nt], acc[mt][nt], 0, 0, 0);
            }
        }
    }
    #pragma unroll
    for (int mt = 0; mt < 2; ++mt) {
        int x0 = wm * 32 + mt * 16 + quad * 4;
        if (x0 >= WW) continue;
        #pragma unroll
        for (int nt = 0; nt < 2; ++nt) {
            int oc = (oh * 4 + wq * 2 + nt) * 16 + lm;
            float bb = bias[oc];
            f32x4 v = acc[mt][nt];
            v[0] += bb; v[1] += bb; v[2] += bb; v[3] += bb;
            *(f32x4*)&out[(((size_t)n * 128 + oc) * HH + y) * WW + x0] = v;
        }
    }
}

// ---------------------------------------------------------------------------
extern "C" void kernel_launch(void* const* d_in, const int* in_sizes, int n_in,
                              void* d_out, int out_size, void* d_ws, size_t ws_size,
                              hipStream_t stream) {
    const float* cnn    = (const float*)d_in[0];
    const float* orig   = (const float*)d_in[1];
    const float* xy     = (const float*)d_in[2];
    const float* g_w0   = (const float*)d_in[3];
    const float* g_b0   = (const float*)d_in[4];
    const float* g_a0   = (const float*)d_in[5];
    const float* g_w1   = (const float*)d_in[6];
    const float* g_b1   = (const float*)d_in[7];
    const float* g_a1   = (const float*)d_in[8];
    const float* q_w    = (const float*)d_in[9];
    const float* q_b    = (const float*)d_in[10];
    const float* q_a    = (const float*)d_in[11];
    const float* conv_w = (const float*)d_in[12];
    const float* conv_b = (const float*)d_in[13];
    float* out = (float*)d_out;

    float* ws = (float*)d_ws;
    const size_t SB = (size_t)MROWS * 128;      // bf16 activation plane count
    __bf16* cnn_b  = (__bf16*)ws;               // SB bf16
    __bf16* h_b    = cnn_b + SB;
    __bf16* tgb    = h_b + SB;
    float*  proj   = (float*)(tgb + SB);        // 64,800 fl
    int*    knn_i  = (int*)(proj + 64800);      // 345,600 int
    __bf16* g0f    = (__bf16*)(knn_i + (size_t)MROWS * KNN);
    __bf16* g1f    = g0f + 16384;
    __bf16* qf     = g1f + 16384;               // 32,768 bf16
    __bf16* w_frag = qf + 32768;                // 294,912 bf16
    __bf16* pad_in = w_frag + 294912;           // 6,545,408 bf16

    setup_all<<<2720 + 16200 + 1408 + 496, 256, 0, stream>>>(
        cnn, xy, orig, g_w0, g_w1, q_w, conv_w,
        cnn_b, pad_in, proj, g0f, g1f, qf, w_frag);
    knn_kernel<<<dim3(338, NB), 512, 0, stream>>>(proj, knn_i);

    // GNN iteration 1
    fused_g<<<675, 256, 0, stream>>>(cnn_b, g0f, g_b0, g_a0, g1f, g_b1, g_a1, tgb);
    fused_q<<<675, 256, 0, stream>>>(cnn_b, tgb, knn_i, qf, q_b, q_a, h_b, pad_in, 0);

    // GNN iteration 2 (second fused_q scatters straight into conv staging)
    fused_g<<<675, 256, 0, stream>>>(h_b, g0f, g_b0, g_a0, g1f, g_b1, g_a1, tgb);
    fused_q<<<675, 256, 0, stream>>>(h_b, tgb, knn_i, qf, q_b, q_a, h_b, pad_in, 1);

    // Conv epilogue
    conv_mfma<<<dim3(HH, 2, NB), 256, 0, stream>>>(pad_in, w_frag, conv_b, out);
}

// Round 11
// 230.371 us; speedup vs baseline: 1.3764x; 1.0597x over previous
//
#include <hip/hip_runtime.h>
#include <cfloat>
#include <cmath>

#define NB 8
#define CC 128
#define HH 45
#define WW 60
#define HWP 2700      // H*W
#define KNN 16
#define H0 360
#define W0 480
#define NT 43         // ceil(2700/64) candidates per lane
#define MROWS 21600   // NB * HWP

typedef __bf16 bf16_8 __attribute__((ext_vector_type(8)));
typedef __bf16 bf16_4 __attribute__((ext_vector_type(4)));
typedef float  f32x4  __attribute__((ext_vector_type(4)));

// ---------------------------------------------------------------------------
// 0) Fused setup: transpose+bf16-cast (2720 blk) | median pool (16200 blk) |
//    weight fragment prep (1408 blk) | pad halo zero (496 blk)
// ---------------------------------------------------------------------------
template <int K>
__device__ __forceinline__ void wfrag_body(const float* __restrict__ Wt,
                                           __bf16* __restrict__ wf, int bx, int tid) {
    int t = bx * 256 + tid;
    int j = t & 7;
    int lane = (t >> 3) & 63;
    int nt = (t >> 9) & 7;
    int kc = t >> 12;
    int oc = nt * 16 + (lane & 15);
    int k = kc * 32 + (lane >> 4) * 8 + j;
    wf[t] = (__bf16)Wt[(size_t)oc * K + k];
}

__global__ void __launch_bounds__(256) setup_all(
    const float* __restrict__ cnn, const float* __restrict__ xy,
    const float* __restrict__ orig,
    const float* __restrict__ g_w0, const float* __restrict__ g_w1,
    const float* __restrict__ q_w, const float* __restrict__ conv_w,
    __bf16* __restrict__ cnn_b, __bf16* __restrict__ pad_in,
    float* __restrict__ proj,
    __bf16* __restrict__ g0f, __bf16* __restrict__ g1f,
    __bf16* __restrict__ qf, __bf16* __restrict__ w_frag) {
    int bx = blockIdx.x;
    int tid = threadIdx.x;
    if (bx < 2720) {
        // ---- transpose (N,128,HW) -> cnn_b + pad_in ch 0..127 ----
        __shared__ float tile[32][33];
        int n = bx / 340;
        int r2 = bx % 340;
        int c0 = (r2 / 85) * 32;
        int p0 = (r2 % 85) * 32;
        int tx = tid & 31, ty = tid >> 5;
        #pragma unroll
        for (int r = 0; r < 32; r += 8) {
            int c = c0 + ty + r, p = p0 + tx;
            tile[ty + r][tx] = (p < HWP) ? cnn[((size_t)n * CC + c) * HWP + p] : 0.f;
        }
        __syncthreads();
        #pragma unroll
        for (int r = 0; r < 32; r += 8) {
            int p = p0 + ty + r, c = c0 + tx;
            if (p < HWP) {
                __bf16 bv = (__bf16)tile[tx][ty + r];
                cnn_b[((size_t)n * HWP + p) * 128 + c] = bv;
                int y = p / WW, x = p % WW;
                pad_in[(((size_t)n * 47 + y + 1) * 68 + (x + 1)) * 256 + c] = bv;
            }
        }
    } else if (bx < 2720 + 16200) {
        // ---- median pool 8x8: bitonic sort, lane 31 = lower median ----
        int w = (bx - 2720) * 4 + (tid >> 6);
        int lane = tid & 63;
        int n = w / (3 * HWP);
        int rem = w % (3 * HWP);
        int c = rem / HWP;
        int b = rem % HWP;
        const float* src = (c < 2) ? (xy + ((size_t)n * 2 + c) * H0 * W0)
                                   : (orig + ((size_t)n * 4 + 3) * H0 * W0);
        int by = b / WW, bxp = b % WW;
        int r = lane >> 3, col = lane & 7;
        float v = src[(by * 8 + r) * W0 + bxp * 8 + col];
        #pragma unroll
        for (int k = 2; k <= 64; k <<= 1) {
            #pragma unroll
            for (int j2 = k >> 1; j2 >= 1; j2 >>= 1) {
                float p = __shfl_xor(v, j2, 64);
                bool dir = (lane & k) == 0;
                bool low = (lane & j2) == 0;
                v = (dir == low) ? fminf(v, p) : fmaxf(v, p);
            }
        }
        if (lane == 31) proj[(size_t)c * (NB * HWP) + (size_t)n * HWP + b] = v;
    } else if (bx < 2720 + 16200 + 1408) {
        int pb = bx - (2720 + 16200);
        if (pb < 64)        wfrag_body<128>(g_w0, g0f, pb, tid);
        else if (pb < 128)  wfrag_body<128>(g_w1, g1f, pb - 64, tid);
        else if (pb < 256)  wfrag_body<256>(q_w, qf, pb - 128, tid);
        else {
            int t = (pb - 256) * 256 + tid;          // 294,912
            int j = t & 7;
            int lane = (t >> 3) & 63;
            int ntile = (t >> 9) & 7;
            int icc = (t >> 12) & 7;
            int tap = t >> 15;
            int oc = ntile * 16 + (lane & 15);
            int ic = icc * 32 + (lane >> 4) * 8 + j;
            w_frag[t] = (__bf16)conv_w[((size_t)oc * 256 + ic) * 9 + tap];
        }
    } else {
        // ---- zero 496 halo cells per image (all 256 ch) ----
        int t = (bx - (2720 + 16200 + 1408)) * 256 + tid;
        int cg = t & 31;
        int s = t >> 5;
        int cell = s % 496;
        int n = s / 496;
        int y, x;
        if (cell < 136) { y = (cell < 68) ? 0 : 46; x = cell % 68; }
        else {
            int rem = cell - 136;
            y = 1 + rem / 8;
            int k = rem % 8;
            x = (k == 0) ? 0 : (60 + k);
        }
        bf16_8 z = {};
        *(bf16_8*)&pad_in[(((size_t)n * 47 + y) * 68 + x) * 256 + cg * 8] = z;
    }
}

// ---------------------------------------------------------------------------
// 3) KNN — validated round-10 algorithm (unchanged)
// ---------------------------------------------------------------------------
__global__ void __launch_bounds__(512, 6) knn_kernel(const float* __restrict__ proj,
                                                     int* __restrict__ knn) {
#pragma clang fp contract(off)
    __shared__ float4 pts[HWP];                    // (x, y, z, sq) per candidate
    __shared__ int sbufj[8][64];                   // survivor indices per wave
    __shared__ int scnt[8];
    int n = blockIdx.y;
    const float* px = proj + (size_t)n * HWP;
    const float* py = proj + (size_t)NB * HWP + (size_t)n * HWP;
    const float* pz = proj + (size_t)2 * NB * HWP + (size_t)n * HWP;
    for (int t = threadIdx.x; t < HWP; t += 512) {
        float x = px[t], y = py[t], z = pz[t];
        float4 p;
        p.x = x; p.y = y; p.z = z;
        p.w = (x * x + y * y) + z * z;             // mirrors jnp.sum(proj*proj,-1)
        pts[t] = p;
    }
    __syncthreads();

    int wave = threadIdx.x >> 6;
    int lane = threadIdx.x & 63;
    int i = blockIdx.x * 8 + wave;                 // row (338*8 >= 2700)
    if (i >= HWP) return;                          // no syncs after this point
    float4 pi = pts[i];
    float xi = pi.x, yi = pi.y, zi = pi.z, sqi = pi.w;

    // ---- Pass A: squared distances; lane min; packed u16 upper bounds ----
    unsigned int sdp[22];
    float mn = FLT_MAX;
    #pragma unroll
    for (int t = 0; t < NT; ++t) {
        int j = lane + t * 64;
        unsigned int u = 0xFFFFu;
        if (j < HWP) {
            float4 pj = pts[j];
            float r = fmaf(zi, pj.z, fmaf(yi, pj.y, xi * pj.x));
            float s = (sqi + pj.w) - 2.0f * r;
            mn = fminf(mn, s);
            float sc = fmaxf(s, 0.f);
            u = (__float_as_uint(sc) + 0xFFFFu) >> 16;   // >= sc, <= sc*(1+2^-7)
        }
        if (t & 1) sdp[t >> 1] |= (u << 16);
        else       sdp[t >> 1] = u;
    }

    // ---- Bitonic sort the 64 lane minima ascending; M_s = rank 15 ----
    float v = mn;
    #pragma unroll
    for (int k = 2; k <= 64; k <<= 1) {
        #pragma unroll
        for (int j2 = k >> 1; j2 >= 1; j2 >>= 1) {
            float p = __shfl_xor(v, j2, 64);
            bool dir = (lane & k) == 0;
            bool low = (lane & j2) == 0;
            v = (dir == low) ? fminf(v, p) : fmaxf(v, p);
        }
    }
    float M_s = __shfl(v, 15, 64);
    float M_test = (M_s > 0.f) ? (M_s * 1.0000005f + 1e-37f) : 0.0f;
    float M_t2 = M_test * 1.009f;                  // cover u16 round-up slack
    unsigned int M16 = __float_as_uint(M_t2) >> 16;   // u<=M16 <=> (u<<16)<=M_bits

    // ---- Pass B: atomic-slot compaction of survivor indices ----
    if (lane == 0) scnt[wave] = 0;
    #pragma unroll
    for (int t = 0; t < NT; ++t) {
        unsigned int u = (t & 1) ? (sdp[t >> 1] >> 16) : (sdp[t >> 1] & 0xFFFFu);
        if (u <= M16) {
            int slot = atomicAdd(&scnt[wave], 1);
            if (slot < 64) sbufj[wave][slot] = lane + t * 64;
        }
    }
    int cnt = scnt[wave];

    int myj = 0;
    if (cnt >= KNN && cnt <= 64) {
        // ---- exact (d, idx) keys for survivors; 64-wide u64 bitonic sort ----
        unsigned long long key = ~0ull;
        if (lane < cnt) {
            int j = sbufj[wave][lane];
            float4 pj = pts[j];
            float r = fmaf(zi, pj.z, fmaf(yi, pj.y, xi * pj.x));
            float s = (sqi + pj.w) - 2.0f * r;
            float d = sqrtf(fmaxf(s, 0.f));
            key = ((unsigned long long)__float_as_uint(d) << 32) | (unsigned int)j;
        }
        #pragma unroll
        for (int k = 2; k <= 64; k <<= 1) {
            #pragma unroll
            for (int j2 = k >> 1; j2 >= 1; j2 >>= 1) {
                unsigned long long p = __shfl_xor(key, j2, 64);
                bool dir = (lane & k) == 0;
                bool low = (lane & j2) == 0;
                bool keepmin = (dir == low);
                bool pless = p < key;
                key = (pless == keepmin) ? p : key;
            }
        }
        myj = (int)(unsigned int)(key & 0xffffffffull);
    } else {
        // ---- rare fallback: 16 rounds of lex-argmin rescan (low-register) ----
        float lastd = -FLT_MAX; int lastj = -1;
        #pragma unroll 1
        for (int r = 0; r < KNN; ++r) {
            float bd = FLT_MAX; int bj = 0x7fffffff;
            #pragma unroll 1
            for (int t = 0; t < NT; ++t) {
                int j = lane + t * 64;
                if (j < HWP) {
                    float4 pj = pts[j];
                    float rr = fmaf(zi, pj.z, fmaf(yi, pj.y, xi * pj.x));
                    float s = (sqi + pj.w) - 2.0f * rr;
                    float d = sqrtf(fmaxf(s, 0.f));
                    bool gt = (d > lastd) || (d == lastd && j > lastj);
                    bool lt = (d < bd) || (d == bd && j < bj);
                    if (gt && lt) { bd = d; bj = j; }
                }
            }
            float md = bd; int mj = bj;
            #pragma unroll
            for (int off = 32; off >= 1; off >>= 1) {
                float od = __shfl_xor(md, off, 64);
                int oj = __shfl_xor(mj, off, 64);
                if (od < md || (od == md && oj < mj)) { md = od; mj = oj; }
            }
            if (lane == r) myj = mj;
            lastd = md; lastj = mj;
        }
    }
    if (lane < KNN)
        knn[((size_t)n * HWP + i) * KNN + lane] = myj;
}

// ---------------------------------------------------------------------------
// 5) bf16 GEMM layer (unchanged)
// ---------------------------------------------------------------------------
__device__ __forceinline__ void layer_b(
    const __bf16* __restrict__ src,                // LDS [32][136] bf16
    const __bf16* __restrict__ wf,                 // global fragments
    int wave, int lane, int kc_base, f32x4 acc[2][2]) {
    int quad = lane >> 4, lm = lane & 15;
    const bf16_8* wf8 = (const bf16_8*)wf;
    #pragma unroll
    for (int kc = 0; kc < 4; ++kc) {
        bf16_8 b[2], a[2];
        #pragma unroll
        for (int nt = 0; nt < 2; ++nt)
            b[nt] = *(const bf16_8*)&src[(nt * 16 + lm) * 136 + kc * 32 + quad * 8];
        #pragma unroll
        for (int mt = 0; mt < 2; ++mt)
            a[mt] = wf8[((size_t)(kc_base + kc) * 8 + (wave * 2 + mt)) * 64 + lane];
        #pragma unroll
        for (int mt = 0; mt < 2; ++mt)
            #pragma unroll
            for (int nt = 0; nt < 2; ++nt)
                acc[mt][nt] = __builtin_amdgcn_mfma_f32_16x16x32_bf16(
                    a[mt], b[nt], acc[mt][nt], 0, 0, 0);
    }
}

// ---------------------------------------------------------------------------
// 5a) Fused g-MLP, XCD-swizzled: image = blockIdx&7 -> all blocks of an
//     image land on one XCD (L2 locality for tgb producer/consumer).
//     Grid 680 = 85 chunks x 8 images; tail rows guarded.
// ---------------------------------------------------------------------------
__global__ void __launch_bounds__(256) fused_g(
    const __bf16* __restrict__ Ain,
    const __bf16* __restrict__ w0f, const float* __restrict__ b0, const float* __restrict__ a0p,
    const __bf16* __restrict__ w1f, const float* __restrict__ b1, const float* __restrict__ a1p,
    __bf16* __restrict__ tgb) {
    __shared__ __bf16 albuf[32 * 136];
    __shared__ __bf16 inter[32 * 136];
    int bx = blockIdx.x;
    int nimg = bx & 7;
    int r0 = (bx >> 3) * 32;                 // row within image, 0..2688
    size_t base = (size_t)nimg * HWP;
    int tid = threadIdx.x;
    int wave = tid >> 6, lane = tid & 63;
    int quad = lane >> 4, lm = lane & 15;
    #pragma unroll
    for (int t = tid; t < 512; t += 256) {
        int row = t >> 4, c8 = (t & 15) * 8;
        int gr = r0 + row; if (gr >= HWP) gr = HWP - 1;       // clamped (discarded later)
        *(bf16_8*)&albuf[row * 136 + c8] =
            *(const bf16_8*)&Ain[(base + gr) * 128 + c8];
    }
    __syncthreads();
    // layer 0
    {
        f32x4 acc[2][2] = {};
        layer_b(albuf, w0f, wave, lane, 0, acc);
        float alpha = a0p[0];
        #pragma unroll
        for (int mt = 0; mt < 2; ++mt) {
            int oc0 = wave * 32 + mt * 16 + quad * 4;
            float4 bb = *(const float4*)&b0[oc0];
            float bv[4] = {bb.x, bb.y, bb.z, bb.w};
            #pragma unroll
            for (int nt = 0; nt < 2; ++nt) {
                bf16_4 o;
                #pragma unroll
                for (int reg = 0; reg < 4; ++reg) {
                    float vv = acc[mt][nt][reg] + bv[reg];
                    vv = (vv >= 0.f) ? vv : alpha * vv;
                    o[reg] = (__bf16)vv;
                }
                *(bf16_4*)&inter[(nt * 16 + lm) * 136 + oc0] = o;
            }
        }
    }
    __syncthreads();
    // layer 1
    {
        f32x4 acc[2][2] = {};
        layer_b(inter, w1f, wave, lane, 0, acc);
        float alpha = a1p[0];
        #pragma unroll
        for (int mt = 0; mt < 2; ++mt) {
            int oc0 = wave * 32 + mt * 16 + quad * 4;
            float4 bb = *(const float4*)&b1[oc0];
            float bv[4] = {bb.x, bb.y, bb.z, bb.w};
            #pragma unroll
            for (int nt = 0; nt < 2; ++nt) {
                bf16_4 o;
                #pragma unroll
                for (int reg = 0; reg < 4; ++reg) {
                    float vv = acc[mt][nt][reg] + bv[reg];
                    vv = (vv >= 0.f) ? vv : alpha * vv;
                    o[reg] = (__bf16)vv;
                }
                int grow = r0 + nt * 16 + lm;
                if (grow < HWP)
                    *(bf16_4*)&tgb[(base + grow) * 128 + oc0] = o;
            }
        }
    }
}

// ---------------------------------------------------------------------------
// 5b) Fused gather-mean + q-GEMM, XCD-swizzled (image = blockIdx&7).
//     mode 0: bf16 linear h_b. mode 1: scatter into pad_in ch 128..255.
// ---------------------------------------------------------------------------
__global__ void __launch_bounds__(256) fused_q(
    const __bf16* __restrict__ Ain, const __bf16* __restrict__ tgb,
    const int* __restrict__ knn_idx,
    const __bf16* __restrict__ qf, const float* __restrict__ qb,
    const float* __restrict__ qap,
    __bf16* __restrict__ out_lin, __bf16* __restrict__ pad_out, int mode) {
    __shared__ __bf16 hlds[32 * 136];
    __shared__ __bf16 mlds[32 * 136];
    int bx = blockIdx.x;
    int nimg = bx & 7;
    int r0 = (bx >> 3) * 32;
    size_t base = (size_t)nimg * HWP;
    int tid = threadIdx.x;
    int wave = tid >> 6, lane = tid & 63;
    int quad = lane >> 4, lm = lane & 15;
    #pragma unroll
    for (int t = tid; t < 512; t += 256) {
        int row = t >> 4, c8 = (t & 15) * 8;
        int gr = r0 + row; if (gr >= HWP) gr = HWP - 1;
        *(bf16_8*)&hlds[row * 136 + c8] =
            *(const bf16_8*)&Ain[(base + gr) * 128 + c8];
    }
    {   // gather + mean: thread handles (pix, 16 channels)
        int pix = tid >> 3;
        int oct0 = (tid & 7) * 2;
        int grow = r0 + pix; if (grow >= HWP) grow = HWP - 1;
        const int* kn = knn_idx + (base + grow) * KNN;
        const __bf16* tbase = tgb + base * 128;
        float a0[8] = {}, a1[8] = {};
        #pragma unroll
        for (int k = 0; k < KNN; ++k) {
            int j = kn[k];
            const __bf16* srcp = tbase + (size_t)j * 128 + oct0 * 8;
            bf16_8 v0 = *(const bf16_8*)srcp;
            bf16_8 v1 = *(const bf16_8*)(srcp + 8);
            #pragma unroll
            for (int e = 0; e < 8; ++e) { a0[e] += (float)v0[e]; a1[e] += (float)v1[e]; }
        }
        const float s = 1.f / 16.f;
        bf16_8 o0, o1;
        #pragma unroll
        for (int e = 0; e < 8; ++e) { o0[e] = (__bf16)(a0[e] * s); o1[e] = (__bf16)(a1[e] * s); }
        *(bf16_8*)&mlds[pix * 136 + oct0 * 8] = o0;
        *(bf16_8*)&mlds[pix * 136 + oct0 * 8 + 8] = o1;
    }
    __syncthreads();
    f32x4 acc[2][2] = {};
    layer_b(hlds, qf, wave, lane, 0, acc);   // k 0..127 (h part)
    layer_b(mlds, qf, wave, lane, 4, acc);   // k 128..255 (m part)
    float alpha = qap[0];
    #pragma unroll
    for (int mt = 0; mt < 2; ++mt) {
        int oc0 = wave * 32 + mt * 16 + quad * 4;
        float4 bb = *(const float4*)&qb[oc0];
        float bv[4] = {bb.x, bb.y, bb.z, bb.w};
        #pragma unroll
        for (int nt = 0; nt < 2; ++nt) {
            bf16_4 o;
            #pragma unroll
            for (int reg = 0; reg < 4; ++reg) {
                float vv = acc[mt][nt][reg] + bv[reg];
                vv = (vv >= 0.f) ? vv : alpha * vv;
                o[reg] = (__bf16)vv;
            }
            int grow = r0 + nt * 16 + lm;
            if (grow < HWP) {
                if (mode == 0) {
                    *(bf16_4*)&out_lin[(base + grow) * 128 + oc0] = o;
                } else {
                    int y = grow / WW, x = grow % WW;
                    *(bf16_4*)&pad_out[(((size_t)nimg * 47 + y + 1) * 68 + (x + 1)) * 256 + 128 + oc0] = o;
                }
            }
        }
    }
}

// ---------------------------------------------------------------------------
// 6) Conv 3x3 MFMA, XCD-swizzled flat grid (720): image = blockIdx&7.
// ---------------------------------------------------------------------------
__global__ void __launch_bounds__(256) conv_mfma(
    const __bf16* __restrict__ pad_in,   // (N,47,68,256)
    const __bf16* __restrict__ w_frag,   // fragment-ordered weights
    const float* __restrict__ bias,
    float* __restrict__ out) {           // (N,128,45,60)
    __shared__ __bf16 alds[3 * 66 * 72];         // [dy][px 0..65][ic 0..63], stride 72
    int bx = blockIdx.x;
    int n = bx & 7;
    int rest = bx >> 3;                  // 0..89
    int y = rest % HH;
    int oh = rest / HH;
    int tid = threadIdx.x;
    int wave = tid >> 6, lane = tid & 63;
    int wm = wave & 1, wq = wave >> 1;
    int quad = lane >> 4, lm = lane & 15;

    f32x4 acc[2][2] = {};
    const bf16_8* wf = (const bf16_8*)w_frag;

    for (int c64 = 0; c64 < 4; ++c64) {
        __syncthreads();
        for (int t = tid; t < 1584; t += 256) {  // 3*66*8 x 16B
            int cq = t & 7;
            int xp = (t >> 3) % 66;
            int dy = (t >> 3) / 66;
            size_t src = (((size_t)n * 47 + (y + dy)) * 68 + xp) * 256 + c64 * 64 + cq * 8;
            *(bf16_8*)&alds[(dy * 66 + xp) * 72 + cq * 8] = *(const bf16_8*)&pad_in[src];
        }
        __syncthreads();
        #pragma unroll
        for (int tap = 0; tap < 9; ++tap) {
            int ky = tap / 3, kx = tap % 3;
            #pragma unroll
            for (int h = 0; h < 2; ++h) {
                int icc = c64 * 2 + h;
                bf16_8 b[2], a[2];
                #pragma unroll
                for (int nt = 0; nt < 2; ++nt)
                    b[nt] = wf[(((tap * 8 + icc) * 8) + (oh * 4 + wq * 2 + nt)) * 64 + lane];
                #pragma unroll
                for (int mt = 0; mt < 2; ++mt)
                    a[mt] = *(const bf16_8*)&alds[(ky * 66 + (wm * 32 + mt * 16 + lm + kx)) * 72
                                                  + h * 32 + quad * 8];
                #pragma unroll
                for (int mt = 0; mt < 2; ++mt)
                    #pragma unroll
                    for (int nt = 0; nt < 2; ++nt)
                        acc[mt][nt] = __builtin_amdgcn_mfma_f32_16x16x32_bf16(
                            a[mt], b[nt], acc[mt][nt], 0, 0, 0);
            }
        }
    }
    #pragma unroll
    for (int mt = 0; mt < 2; ++mt) {
        int x0 = wm * 32 + mt * 16 + quad * 4;
        if (x0 >= WW) continue;
        #pragma unroll
        for (int nt = 0; nt < 2; ++nt) {
            int oc = (oh * 4 + wq * 2 + nt) * 16 + lm;
            float bb = bias[oc];
            f32x4 v = acc[mt][nt];
            v[0] += bb; v[1] += bb; v[2] += bb; v[3] += bb;
            *(f32x4*)&out[(((size_t)n * 128 + oc) * HH + y) * WW + x0] = v;
        }
    }
}

// ---------------------------------------------------------------------------
extern "C" void kernel_launch(void* const* d_in, const int* in_sizes, int n_in,
                              void* d_out, int out_size, void* d_ws, size_t ws_size,
                              hipStream_t stream) {
    const float* cnn    = (const float*)d_in[0];
    const float* orig   = (const float*)d_in[1];
    const float* xy     = (const float*)d_in[2];
    const float* g_w0   = (const float*)d_in[3];
    const float* g_b0   = (const float*)d_in[4];
    const float* g_a0   = (const float*)d_in[5];
    const float* g_w1   = (const float*)d_in[6];
    const float* g_b1   = (const float*)d_in[7];
    const float* g_a1   = (const float*)d_in[8];
    const float* q_w    = (const float*)d_in[9];
    const float* q_b    = (const float*)d_in[10];
    const float* q_a    = (const float*)d_in[11];
    const float* conv_w = (const float*)d_in[12];
    const float* conv_b = (const float*)d_in[13];
    float* out = (float*)d_out;

    float* ws = (float*)d_ws;
    const size_t SB = (size_t)MROWS * 128;      // bf16 activation plane count
    __bf16* cnn_b  = (__bf16*)ws;               // SB bf16
    __bf16* h_b    = cnn_b + SB;
    __bf16* tgb    = h_b + SB;
    float*  proj   = (float*)(tgb + SB);        // 64,800 fl
    int*    knn_i  = (int*)(proj + 64800);      // 345,600 int
    __bf16* g0f    = (__bf16*)(knn_i + (size_t)MROWS * KNN);
    __bf16* g1f    = g0f + 16384;
    __bf16* qf     = g1f + 16384;               // 32,768 bf16
    __bf16* w_frag = qf + 32768;                // 294,912 bf16
    __bf16* pad_in = w_frag + 294912;           // 6,545,408 bf16

    setup_all<<<2720 + 16200 + 1408 + 496, 256, 0, stream>>>(
        cnn, xy, orig, g_w0, g_w1, q_w, conv_w,
        cnn_b, pad_in, proj, g0f, g1f, qf, w_frag);
    knn_kernel<<<dim3(338, NB), 512, 0, stream>>>(proj, knn_i);

    // GNN iteration 1
    fused_g<<<680, 256, 0, stream>>>(cnn_b, g0f, g_b0, g_a0, g1f, g_b1, g_a1, tgb);
    fused_q<<<680, 256, 0, stream>>>(cnn_b, tgb, knn_i, qf, q_b, q_a, h_b, pad_in, 0);

    // GNN iteration 2 (second fused_q scatters straight into conv staging)
    fused_g<<<680, 256, 0, stream>>>(h_b, g0f, g_b0, g_a0, g1f, g_b1, g_a1, tgb);
    fused_q<<<680, 256, 0, stream>>>(h_b, tgb, knn_i, qf, q_b, q_a, h_b, pad_in, 1);

    // Conv epilogue
    conv_mfma<<<720, 256, 0, stream>>>(pad_in, w_frag, conv_b, out);
}